// Round 5
// baseline (1184.490 us; speedup 1.0000x reference)
//
#include <hip/hip_runtime.h>

#define HW_T 1024
#define HW_S 4096

// ---------------------------------------------------------------------------
// Kernel 1: fused Q & K 1x1 conv.  Q[b][cq][hw] = sum_c qw[cq][c]*rgb[c][hw]+qb
// NO LDS: weights are wave-uniform -> read straight from global; the compiler
// proves uniformity and emits s_load into SGPRs (scalar pipe), v_fmac takes
// the SGPR operand.  c unrolled x8 so scalar loads merge to dwordx8 and stay
// sequential (K$-friendly).  Zero DS traffic, zero barriers.
// grid (16, 64): y -> (branch, batch); x*256 -> hw chunk (t exits x>=4).
// ---------------------------------------------------------------------------
__global__ __launch_bounds__(256)
void qk_kernel(const float* __restrict__ rgb_t, const float* __restrict__ rgb_s,
               const float* __restrict__ qw_t, const float* __restrict__ kw_t,
               const float* __restrict__ qw_s, const float* __restrict__ kw_s,
               const float* __restrict__ qb_t, const float* __restrict__ kb_t,
               const float* __restrict__ qb_s, const float* __restrict__ kb_s,
               float* __restrict__ Q_t, float* __restrict__ K_t,
               float* __restrict__ Q_s, float* __restrict__ K_s) {
    const int zb = blockIdx.y, br = zb >> 5, b = zb & 31;
    const int HW = br ? HW_S : HW_T;
    if ((int)blockIdx.x * 256 >= HW) return;   // whole-block uniform exit

    const float* qw = br ? qw_s : qw_t;
    const float* kw = br ? kw_s : kw_t;
    const float* qb = br ? qb_s : qb_t;
    const float* kb = br ? kb_s : kb_t;

    float qacc[32], kacc[32];
#pragma unroll
    for (int cq = 0; cq < 32; cq++) { qacc[cq] = qb[cq]; kacc[cq] = kb[cq]; }

    const int hw = blockIdx.x * 256 + threadIdx.x;
    const float* rgb = (br ? rgb_s : rgb_t) + (size_t)b * 256 * HW + hw;

    for (int c0 = 0; c0 < 256; c0 += 8) {
        const float r0 = rgb[(size_t)(c0 + 0) * HW];
        const float r1 = rgb[(size_t)(c0 + 1) * HW];
        const float r2 = rgb[(size_t)(c0 + 2) * HW];
        const float r3 = rgb[(size_t)(c0 + 3) * HW];
        const float r4 = rgb[(size_t)(c0 + 4) * HW];
        const float r5 = rgb[(size_t)(c0 + 5) * HW];
        const float r6 = rgb[(size_t)(c0 + 6) * HW];
        const float r7 = rgb[(size_t)(c0 + 7) * HW];
#pragma unroll
        for (int cq = 0; cq < 32; cq++) {
            const float* wq = qw + cq * 256 + c0;   // uniform -> s_load_dwordx8
            const float* wk = kw + cq * 256 + c0;
            float qa = qacc[cq], ka = kacc[cq];
            qa = fmaf(r0, wq[0], qa); ka = fmaf(r0, wk[0], ka);
            qa = fmaf(r1, wq[1], qa); ka = fmaf(r1, wk[1], ka);
            qa = fmaf(r2, wq[2], qa); ka = fmaf(r2, wk[2], ka);
            qa = fmaf(r3, wq[3], qa); ka = fmaf(r3, wk[3], ka);
            qa = fmaf(r4, wq[4], qa); ka = fmaf(r4, wk[4], ka);
            qa = fmaf(r5, wq[5], qa); ka = fmaf(r5, wk[5], ka);
            qa = fmaf(r6, wq[6], qa); ka = fmaf(r6, wk[6], ka);
            qa = fmaf(r7, wq[7], qa); ka = fmaf(r7, wk[7], ka);
            qacc[cq] = qa; kacc[cq] = ka;
        }
    }

    float* Q = (br ? Q_s : Q_t) + (size_t)b * 32 * HW + hw;
    float* K = (br ? K_s : K_t) + (size_t)b * 32 * HW + hw;
#pragma unroll
    for (int cq = 0; cq < 32; cq++) {
        Q[(size_t)cq * HW] = qacc[cq];
        K[(size_t)cq * HW] = kacc[cq];
    }
}

// ---------------------------------------------------------------------------
// Kernel 2: energy (Qr @ Kr^T over M) + reversed-softmax -> attn (fp32)
// (unchanged this round)
// ---------------------------------------------------------------------------
__global__ __launch_bounds__(256)
void attn_kernel(const float* __restrict__ Q_t, const float* __restrict__ K_t,
                 const float* __restrict__ Q_s, const float* __restrict__ K_s,
                 float* __restrict__ A_t, float* __restrict__ A_s) {
    const int zb = blockIdx.y, br = zb >> 5, b = zb & 31;
    const int M = br ? (HW_S / 8) : (HW_T / 8);          // 512 / 128
    const float* Qb = (br ? Q_s : Q_t) + (size_t)b * 32 * (br ? HW_S : HW_T);
    const float* Kb = (br ? K_s : K_t) + (size_t)b * 32 * (br ? HW_S : HW_T);
    float* attn = (br ? A_s : A_t) + (size_t)b * 65536;
    const int c0 = blockIdx.x * 32;

    __shared__ float sK[256][33];
    __shared__ float sQ[32][33];
    __shared__ float eT[32][260];

    const int tid = threadIdx.x;
    const int dx = tid & 31, cy = tid >> 5;   // thread covers c = cy*4+i, d = dx+32j
    float acc[4][8] = {};

    for (int m0 = 0; m0 < M; m0 += 32) {
        __syncthreads();
        {
            const int rr = tid >> 3;
            const int cc = (tid & 7) << 2;
#pragma unroll
            for (int p = 0; p < 8; p++) {
                const int row = (p << 5) + rr;
                const float4 v = *(const float4*)(Kb + (size_t)row * M + m0 + cc);
                sK[row][cc] = v.x; sK[row][cc + 1] = v.y;
                sK[row][cc + 2] = v.z; sK[row][cc + 3] = v.w;
            }
            const float4 qv = *(const float4*)(Qb + (size_t)(c0 + rr) * M + m0 + cc);
            sQ[rr][cc] = qv.x; sQ[rr][cc + 1] = qv.y;
            sQ[rr][cc + 2] = qv.z; sQ[rr][cc + 3] = qv.w;
        }
        __syncthreads();
#pragma unroll 2
        for (int m = 0; m < 32; m++) {
            float kv[8];
#pragma unroll
            for (int j = 0; j < 8; j++) kv[j] = sK[dx + (j << 5)][m];
#pragma unroll
            for (int i = 0; i < 4; i++) {
                const float qv = sQ[(cy << 2) + i][m];
#pragma unroll
                for (int j = 0; j < 8; j++) acc[i][j] = fmaf(qv, kv[j], acc[i][j]);
            }
        }
    }

#pragma unroll
    for (int i = 0; i < 4; i++)
#pragma unroll
        for (int j = 0; j < 8; j++)
            eT[(cy << 2) + i][dx + (j << 5)] = acc[i][j];
    __syncthreads();

    // softmax: 8 threads per row (consecutive lanes), 32 cols each (stride 8)
    const int r = tid >> 3, s8 = tid & 7;
    float p[32];
    float mn = 3.0e38f;
#pragma unroll
    for (int m = 0; m < 32; m++) { p[m] = eT[r][s8 + (m << 3)]; mn = fminf(mn, p[m]); }
    mn = fminf(mn, __shfl_xor(mn, 1));
    mn = fminf(mn, __shfl_xor(mn, 2));
    mn = fminf(mn, __shfl_xor(mn, 4));
    float sum = 0.f;
#pragma unroll
    for (int m = 0; m < 32; m++) { p[m] = __expf(mn - p[m]); sum += p[m]; }
    sum += __shfl_xor(sum, 1);
    sum += __shfl_xor(sum, 2);
    sum += __shfl_xor(sum, 4);
    const float rinv = 1.0f / sum;
#pragma unroll
    for (int m = 0; m < 32; m++) eT[r][s8 + (m << 3)] = p[m] * rinv;
    __syncthreads();

    for (int idx = tid; idx < 2048; idx += 256) {
        const int row = idx >> 6, c4 = (idx & 63) << 2;
        const float4 v = *(const float4*)&eT[row][c4];
        *(float4*)(attn + (size_t)(c0 + row) * 256 + c4) = v;
    }
}

// ---------------------------------------------------------------------------
// Kernel 3/5: tiled GEMM  C[c][n] = sum_k A[c][k] * B[k][n]
//   256x128 tile, 256 threads, 16x8 micro-tile: LDS bytes/FLOP drops
//   0.5 -> 0.375 (r4 evidence: dur pinned at 376us with DS read BW at 66%
//   of the 69 TB/s LDS ceiling and DS:VALU issue exactly 1:1 at 8x8).
//   16x8 puts the LDS ceiling (~184 TF) above fp32 peak (157 TF) -> VALU-bound.
//   32 NAMED float4 accumulators (SROA-proof), waves_per_eu(2,2) -> 256-reg
//   budget, no spill.  K-step 32, global reg-prefetch.
//   FINAL=0: store fp32 W' tile.  FINAL=1: out = alpha*(acc + b'[c]) + z.
// grid (ceil(N/128), 1, 64).
// ---------------------------------------------------------------------------
#define FR8(AL, AR, AV)                                       \
    AL.x = fmaf(AV, b0.x, AL.x); AL.y = fmaf(AV, b0.y, AL.y); \
    AL.z = fmaf(AV, b0.z, AL.z); AL.w = fmaf(AV, b0.w, AL.w); \
    AR.x = fmaf(AV, b1.x, AR.x); AR.y = fmaf(AV, b1.y, AR.y); \
    AR.z = fmaf(AV, b1.z, AR.z); AR.w = fmaf(AV, b1.w, AR.w);

#define STA(P, OFF)                                           \
    sAf[(aslot * 4 + 0) * 260 + ar + (OFF)] = P.x;            \
    sAf[(aslot * 4 + 1) * 260 + ar + (OFF)] = P.y;            \
    sAf[(aslot * 4 + 2) * 260 + ar + (OFF)] = P.z;            \
    sAf[(aslot * 4 + 3) * 260 + ar + (OFF)] = P.w;

#define EPI_FIN(AL, AR, CROW) {                               \
    const int c = (CROW);                                     \
    const float bpv = bp[c];                                  \
    const size_t off0 = (size_t)c * N + n0 + (tx << 2);       \
    const float4 z0 = *(const float4*)(Bm + off0);            \
    const float4 z1 = *(const float4*)(Bm + off0 + 64);       \
    float4 o0, o1;                                            \
    o0.x = fmaf(alpha, AL.x + bpv, z0.x);                     \
    o0.y = fmaf(alpha, AL.y + bpv, z0.y);                     \
    o0.z = fmaf(alpha, AL.z + bpv, z0.z);                     \
    o0.w = fmaf(alpha, AL.w + bpv, z0.w);                     \
    o1.x = fmaf(alpha, AR.x + bpv, z1.x);                     \
    o1.y = fmaf(alpha, AR.y + bpv, z1.y);                     \
    o1.z = fmaf(alpha, AR.z + bpv, z1.z);                     \
    o1.w = fmaf(alpha, AR.w + bpv, z1.w);                     \
    *(float4*)(O + off0) = o0;                                \
    *(float4*)(O + off0 + 64) = o1; }

#define EPI_STO(AL, AR, CROW) {                               \
    const int c = (CROW);                                     \
    const size_t off0 = (size_t)c * 256 + n0 + (tx << 2);     \
    *(float4*)(Co + off0) = AL;                               \
    *(float4*)(Co + off0 + 64) = AR; }

template <int FINAL>
__global__ __launch_bounds__(256)
__attribute__((amdgpu_waves_per_eu(2, 2)))
void gemm256(const float* __restrict__ A_t, const float* __restrict__ A_s,
             const float* __restrict__ B_t, const float* __restrict__ B_s,
             float* __restrict__ C_t, float* __restrict__ C_s,
             float* __restrict__ O_t, float* __restrict__ O_s,
             const float* __restrict__ bp_t, const float* __restrict__ bp_s,
             const float* __restrict__ alpha_p, const float* __restrict__ beta_p,
             int N_t, int N_s) {
    const int zb = blockIdx.z, br = zb >> 5, b = zb & 31;
    const int N = br ? N_s : N_t;
    const int n0 = blockIdx.x * 128;
    if (n0 >= N) return;                        // whole-block uniform exit
    const float* A = (br ? A_s : A_t) + (size_t)b * 65536;
    const float* Bm = (br ? B_s : B_t);
    if (FINAL) Bm += (size_t)b * 256 * (size_t)N;

    // k-major LDS tiles; sA row stride 260 floats (stride%32==4: A-scatter
    // writes land 4-way worst-case = negligible; 16B-aligned for b128 reads)
    __shared__ float4 sA4[32][65];              // 256 c per k-row
    __shared__ float4 sB4[32][33];              // 128 n per k-row
    float* sAf = (float*)sA4;

    const int tid = threadIdx.x;
    const int tx = tid & 15, ty = tid >> 4;     // micro-tile coords

    // staging maps (coalesced 128B row chunks):
    const int ar = tid >> 3, aslot = tid & 7;   // A: c-row ar+32p (p0..7), k=aslot*4..
    const int brow = tid >> 5, bcol = tid & 31; // B: k-row brow+8p (p0..3), n=bcol*4..

    const float* Abase = A + (size_t)ar * 256 + aslot * 4;
    const float* Bbase = Bm + (size_t)brow * N + n0 + bcol * 4;

    float4 cL0{}, cL1{}, cL2{}, cL3{}, cL4{}, cL5{}, cL6{}, cL7{};
    float4 cL8{}, cL9{}, cL10{}, cL11{}, cL12{}, cL13{}, cL14{}, cL15{};
    float4 cR0{}, cR1{}, cR2{}, cR3{}, cR4{}, cR5{}, cR6{}, cR7{};
    float4 cR8{}, cR9{}, cR10{}, cR11{}, cR12{}, cR13{}, cR14{}, cR15{};
    float4 pa0, pa1, pa2, pa3, pa4, pa5, pa6, pa7, pb0, pb1, pb2, pb3;

    // prefetch tile k0 = 0 into registers
    pa0 = *(const float4*)(Abase);
    pa1 = *(const float4*)(Abase + 8192);
    pa2 = *(const float4*)(Abase + 16384);
    pa3 = *(const float4*)(Abase + 24576);
    pa4 = *(const float4*)(Abase + 32768);
    pa5 = *(const float4*)(Abase + 40960);
    pa6 = *(const float4*)(Abase + 49152);
    pa7 = *(const float4*)(Abase + 57344);
    pb0 = *(const float4*)(Bbase);
    pb1 = *(const float4*)(Bbase + (size_t)8 * N);
    pb2 = *(const float4*)(Bbase + (size_t)16 * N);
    pb3 = *(const float4*)(Bbase + (size_t)24 * N);

    for (int k0 = 0; k0 < 256; k0 += 32) {
        __syncthreads();                        // LDS free to overwrite
        STA(pa0, 0)   STA(pa1, 32)  STA(pa2, 64)  STA(pa3, 96)
        STA(pa4, 128) STA(pa5, 160) STA(pa6, 192) STA(pa7, 224)
        sB4[brow][bcol]      = pb0;
        sB4[brow + 8][bcol]  = pb1;
        sB4[brow + 16][bcol] = pb2;
        sB4[brow + 24][bcol] = pb3;
        __syncthreads();

        if (k0 + 32 < 256) {                    // prefetch next tile under compute
            const int kn = k0 + 32;
            pa0 = *(const float4*)(Abase + kn);
            pa1 = *(const float4*)(Abase + 8192 + kn);
            pa2 = *(const float4*)(Abase + 16384 + kn);
            pa3 = *(const float4*)(Abase + 24576 + kn);
            pa4 = *(const float4*)(Abase + 32768 + kn);
            pa5 = *(const float4*)(Abase + 40960 + kn);
            pa6 = *(const float4*)(Abase + 49152 + kn);
            pa7 = *(const float4*)(Abase + 57344 + kn);
            pb0 = *(const float4*)(Bbase + (size_t)kn * N);
            pb1 = *(const float4*)(Bbase + (size_t)(kn + 8) * N);
            pb2 = *(const float4*)(Bbase + (size_t)(kn + 16) * N);
            pb3 = *(const float4*)(Bbase + (size_t)(kn + 24) * N);
        }

#pragma unroll 4
        for (int k = 0; k < 32; k++) {
            const float4 a0 = sA4[k][ty];
            const float4 a1 = sA4[k][16 + ty];
            const float4 a2 = sA4[k][32 + ty];
            const float4 a3 = sA4[k][48 + ty];
            const float4 b0 = sB4[k][tx];
            const float4 b1 = sB4[k][16 + tx];
            FR8(cL0,  cR0,  a0.x) FR8(cL1,  cR1,  a0.y)
            FR8(cL2,  cR2,  a0.z) FR8(cL3,  cR3,  a0.w)
            FR8(cL4,  cR4,  a1.x) FR8(cL5,  cR5,  a1.y)
            FR8(cL6,  cR6,  a1.z) FR8(cL7,  cR7,  a1.w)
            FR8(cL8,  cR8,  a2.x) FR8(cL9,  cR9,  a2.y)
            FR8(cL10, cR10, a2.z) FR8(cL11, cR11, a2.w)
            FR8(cL12, cR12, a3.x) FR8(cL13, cR13, a3.y)
            FR8(cL14, cR14, a3.z) FR8(cL15, cR15, a3.w)
        }
    }

    if (FINAL) {
        const float alpha = br ? beta_p[0] : alpha_p[0];
        const float* bp = (br ? bp_s : bp_t) + b * 256;
        float* O = (br ? O_s : O_t) + (size_t)b * 256 * (size_t)N;
        EPI_FIN(cL0,  cR0,  (ty << 2) + 0)
        EPI_FIN(cL1,  cR1,  (ty << 2) + 1)
        EPI_FIN(cL2,  cR2,  (ty << 2) + 2)
        EPI_FIN(cL3,  cR3,  (ty << 2) + 3)
        EPI_FIN(cL4,  cR4,  64 + (ty << 2) + 0)
        EPI_FIN(cL5,  cR5,  64 + (ty << 2) + 1)
        EPI_FIN(cL6,  cR6,  64 + (ty << 2) + 2)
        EPI_FIN(cL7,  cR7,  64 + (ty << 2) + 3)
        EPI_FIN(cL8,  cR8,  128 + (ty << 2) + 0)
        EPI_FIN(cL9,  cR9,  128 + (ty << 2) + 1)
        EPI_FIN(cL10, cR10, 128 + (ty << 2) + 2)
        EPI_FIN(cL11, cR11, 128 + (ty << 2) + 3)
        EPI_FIN(cL12, cR12, 192 + (ty << 2) + 0)
        EPI_FIN(cL13, cR13, 192 + (ty << 2) + 1)
        EPI_FIN(cL14, cR14, 192 + (ty << 2) + 2)
        EPI_FIN(cL15, cR15, 192 + (ty << 2) + 3)
    } else {
        float* Co = (br ? C_s : C_t) + (size_t)b * 65536;
        EPI_STO(cL0,  cR0,  (ty << 2) + 0)
        EPI_STO(cL1,  cR1,  (ty << 2) + 1)
        EPI_STO(cL2,  cR2,  (ty << 2) + 2)
        EPI_STO(cL3,  cR3,  (ty << 2) + 3)
        EPI_STO(cL4,  cR4,  64 + (ty << 2) + 0)
        EPI_STO(cL5,  cR5,  64 + (ty << 2) + 1)
        EPI_STO(cL6,  cR6,  64 + (ty << 2) + 2)
        EPI_STO(cL7,  cR7,  64 + (ty << 2) + 3)
        EPI_STO(cL8,  cR8,  128 + (ty << 2) + 0)
        EPI_STO(cL9,  cR9,  128 + (ty << 2) + 1)
        EPI_STO(cL10, cR10, 128 + (ty << 2) + 2)
        EPI_STO(cL11, cR11, 128 + (ty << 2) + 3)
        EPI_STO(cL12, cR12, 192 + (ty << 2) + 0)
        EPI_STO(cL13, cR13, 192 + (ty << 2) + 1)
        EPI_STO(cL14, cR14, 192 + (ty << 2) + 2)
        EPI_STO(cL15, cR15, 192 + (ty << 2) + 3)
    }
}

// ---------------------------------------------------------------------------
// Kernel 4: b'[b][c] = sum_d attn[b][c][d] * vb[d]   (GEMV; vb is tiny)
// ---------------------------------------------------------------------------
__global__ __launch_bounds__(256)
void bprime_kernel(const float* __restrict__ A_t, const float* __restrict__ A_s,
                   const float* __restrict__ vb_t, const float* __restrict__ vb_s,
                   float* __restrict__ bp_t, float* __restrict__ bp_s) {
    const int bx = blockIdx.x, br = bx >> 5, b = bx & 31;
    const float* A = (br ? A_s : A_t) + (size_t)b * 65536;
    const float* vb = br ? vb_s : vb_t;
    float* bp = (br ? bp_s : bp_t) + b * 256;
    __shared__ float svb[256];
    svb[threadIdx.x] = vb[threadIdx.x];
    __syncthreads();
    const int wave = threadIdx.x >> 6, lane = threadIdx.x & 63;
    for (int c = wave; c < 256; c += 4) {
        const float4 a = *(const float4*)(A + (size_t)c * 256 + (lane << 2));
        const int l4 = lane << 2;
        float s = a.x * svb[l4] + a.y * svb[l4 + 1] + a.z * svb[l4 + 2] + a.w * svb[l4 + 3];
#pragma unroll
        for (int off = 32; off > 0; off >>= 1) s += __shfl_down(s, off);
        if (lane == 0) bp[c] = s;
    }
}

// ---------------------------------------------------------------------------
extern "C" void kernel_launch(void* const* d_in, const int* in_sizes, int n_in,
                              void* d_out, int out_size, void* d_ws, size_t ws_size,
                              hipStream_t stream) {
    const float* rgb_t = (const float*)d_in[0];
    const float* rgb_s = (const float*)d_in[1];
    const float* z_t   = (const float*)d_in[2];
    const float* z_s   = (const float*)d_in[3];
    const float* tq_w  = (const float*)d_in[4];
    const float* tq_b  = (const float*)d_in[5];
    const float* tk_w  = (const float*)d_in[6];
    const float* tk_b  = (const float*)d_in[7];
    const float* tv_w  = (const float*)d_in[8];
    const float* tv_b  = (const float*)d_in[9];
    const float* sq_w  = (const float*)d_in[10];
    const float* sq_b  = (const float*)d_in[11];
    const float* sk_w  = (const float*)d_in[12];
    const float* sk_b  = (const float*)d_in[13];
    const float* sv_w  = (const float*)d_in[14];
    const float* sv_b  = (const float*)d_in[15];
    const float* alpha = (const float*)d_in[16];
    const float* beta  = (const float*)d_in[17];

    // workspace layout (fp32).  W' aliases the Q/K region (attn is the last
    // reader of Q/K; gemm256<0> runs after attn_kernel).  Total ~58.8 MB.
    float* ws  = (float*)d_ws;
    float* At  = ws;                       // 32*256*256   attn (t)
    float* As_ = At + 2097152;             // attn (s)
    float* bt  = As_ + 2097152;            // 32*256 b' (t)
    float* bs  = bt + 8192;                // b' (s)
    float* Qt  = bs + 8192;                // 32*32*1024
    float* Kt  = Qt + 1048576;
    float* Qs  = Kt + 1048576;             // 32*32*4096
    float* Ks  = Qs + 4194304;
    float* Wt  = Qt;                       // alias: W' (t) over Qt/Kt
    float* Ws_ = Qs;                       // alias: W' (s) over Qs

    float* out_t = (float*)d_out;
    float* out_s = out_t + (size_t)32 * 256 * HW_T;   // 8,388,608 elements

    qk_kernel<<<dim3(16, 64), 256, 0, stream>>>(
        rgb_t, rgb_s, tq_w, tk_w, sq_w, sk_w,
        tq_b, tk_b, sq_b, sk_b, Qt, Kt, Qs, Ks);

    attn_kernel<<<dim3(8, 64), 256, 0, stream>>>(Qt, Kt, Qs, Ks, At, As_);

    bprime_kernel<<<dim3(64), 256, 0, stream>>>(At, As_, tv_b, sv_b, bt, bs);

    gemm256<0><<<dim3(2, 1, 64), 256, 0, stream>>>(
        At, As_, tv_w, sv_w, Wt, Ws_,
        (float*)nullptr, (float*)nullptr, (const float*)nullptr, (const float*)nullptr,
        (const float*)nullptr, (const float*)nullptr, 256, 256);

    gemm256<1><<<dim3(32, 1, 64), 256, 0, stream>>>(
        Wt, Ws_, z_t, z_s, (float*)nullptr, (float*)nullptr,
        out_t, out_s, bt, bs, alpha, beta, HW_T, HW_S);
}

// Round 6
// 891.901 us; speedup vs baseline: 1.3281x; 1.3281x over previous
//
#include <hip/hip_runtime.h>

#define HW_T 1024
#define HW_S 4096

// ---------------------------------------------------------------------------
// Kernel 0: wprep — transpose weights to k-major Wc[c][row]: row<32 -> qw,
// row>=32 -> kw.  Tiny one-time cost; makes qk_gemm staging coalesced.
// grid (2): x = branch.
// ---------------------------------------------------------------------------
__global__ __launch_bounds__(256)
void wprep_kernel(const float* __restrict__ qw_t, const float* __restrict__ kw_t,
                  const float* __restrict__ qw_s, const float* __restrict__ kw_s,
                  float* __restrict__ Wc_t, float* __restrict__ Wc_s) {
    const int br = blockIdx.x;
    const float* qw = br ? qw_s : qw_t;
    const float* kw = br ? kw_s : kw_t;
    float* Wc = br ? Wc_s : Wc_t;
    const int c = threadIdx.x;                 // 256 threads = 256 channels
#pragma unroll 4
    for (int cq = 0; cq < 32; cq++) {
        Wc[c * 64 + cq]      = qw[cq * 256 + c];   // coalesced reads
        Wc[c * 64 + 32 + cq] = kw[cq * 256 + c];
    }
}

// ---------------------------------------------------------------------------
// Kernel 1: qk_gemm — Q/K 1x1 conv as a 64x512-tile GEMM.
//   Rows = 64 (32 Q + 32 K), K = 256 channels, N = HW.
//   16x8 micro-tile (4 waves x 64 n-threads); A-operand (weights) reads are
//   WAVE-UNIFORM LDS broadcasts (near-free) -> DS/VALU ~0.5 -> VALU-bound.
//   (r5 evidence: s_load-weight design was latency-bound at 37% VALUBusy,
//    2.5 blocks/CU; rounds 0-4 LDS-broadcast design was DS-bound 3:1.)
//   K-step 16, reg prefetch, named accumulators (SROA-proof), waves_per_eu(2,2).
// grid (8, 64): y -> (branch, batch); x*512 -> hw chunk (t exits x>=2).
// ---------------------------------------------------------------------------
#define FR8(AL, AR, AV)                                       \
    AL.x = fmaf(AV, b0.x, AL.x); AL.y = fmaf(AV, b0.y, AL.y); \
    AL.z = fmaf(AV, b0.z, AL.z); AL.w = fmaf(AV, b0.w, AL.w); \
    AR.x = fmaf(AV, b1.x, AR.x); AR.y = fmaf(AV, b1.y, AR.y); \
    AR.z = fmaf(AV, b1.z, AR.z); AR.w = fmaf(AV, b1.w, AR.w);

#define QK_OUT(ACL, ACR, RI) {                                \
    const int row = (g << 4) + (RI);                          \
    const float bv = (row < 32) ? qb[row] : kb[row & 31];     \
    float* Op = ((row < 32) ? Qo : Ko)                        \
                + (size_t)(row & 31) * HW + n0 + (j << 2);    \
    float4 o0, o1;                                            \
    o0.x = ACL.x + bv; o0.y = ACL.y + bv;                     \
    o0.z = ACL.z + bv; o0.w = ACL.w + bv;                     \
    o1.x = ACR.x + bv; o1.y = ACR.y + bv;                     \
    o1.z = ACR.z + bv; o1.w = ACR.w + bv;                     \
    *(float4*)(Op) = o0;                                      \
    *(float4*)(Op + 256) = o1; }

__global__ __launch_bounds__(256)
__attribute__((amdgpu_waves_per_eu(2, 2)))
void qk_gemm(const float* __restrict__ rgb_t, const float* __restrict__ rgb_s,
             const float* __restrict__ Wc_t, const float* __restrict__ Wc_s,
             const float* __restrict__ qb_t, const float* __restrict__ kb_t,
             const float* __restrict__ qb_s, const float* __restrict__ kb_s,
             float* __restrict__ Q_t, float* __restrict__ K_t,
             float* __restrict__ Q_s, float* __restrict__ K_s) {
    const int zb = blockIdx.y, br = zb >> 5, b = zb & 31;
    const int HW = br ? HW_S : HW_T;
    const int n0 = blockIdx.x * 512;
    if (n0 >= HW) return;                       // whole-block uniform exit

    const float* rgb = (br ? rgb_s : rgb_t) + (size_t)b * 256 * HW;
    const float* Wc  = br ? Wc_s : Wc_t;        // [256 c][64 row] k-major
    const float* qb  = br ? qb_s : qb_t;
    const float* kb  = br ? kb_s : kb_t;

    __shared__ float4 sW4[16][16];              // [k][row/4]   4 KiB
    __shared__ float4 sB4[16][129];             // [k][col/4]  ~33 KiB (pad skews rows)

    const int tid = threadIdx.x;
    const int g = tid >> 6;                     // wave id: rows g*16..g*16+15
    const int j = tid & 63;                     // n-thread: cols n0+j*4, n0+256+j*4

    // staging maps
    const int wk = tid >> 4, wr = tid & 15;     // sW: k-row wk, float4 wr
    const int bk = tid >> 4, bj = tid & 15;     // sB: k-row bk, 8 float4 at bj+16p

    const float* Wbase = Wc + (size_t)wk * 64 + wr * 4;
    const float* Bbase = rgb + (size_t)bk * HW + n0 + bj * 4;

    float4 u0{}, u1{}, u2{}, u3{}, u4{}, u5{}, u6{}, u7{};
    float4 u8{}, u9{}, u10{}, u11{}, u12{}, u13{}, u14{}, u15{};
    float4 v0{}, v1{}, v2{}, v3{}, v4{}, v5{}, v6{}, v7{};
    float4 v8{}, v9{}, v10{}, v11{}, v12{}, v13{}, v14{}, v15{};
    float4 pw, pb0, pb1, pb2, pb3, pb4, pb5, pb6, pb7;

    // prefetch k0 = 0
    pw  = *(const float4*)(Wbase);
    pb0 = *(const float4*)(Bbase);
    pb1 = *(const float4*)(Bbase + 64);
    pb2 = *(const float4*)(Bbase + 128);
    pb3 = *(const float4*)(Bbase + 192);
    pb4 = *(const float4*)(Bbase + 256);
    pb5 = *(const float4*)(Bbase + 320);
    pb6 = *(const float4*)(Bbase + 384);
    pb7 = *(const float4*)(Bbase + 448);

    for (int k0 = 0; k0 < 256; k0 += 16) {
        __syncthreads();
        sW4[wk][wr] = pw;
        sB4[bk][bj]       = pb0;
        sB4[bk][bj + 16]  = pb1;
        sB4[bk][bj + 32]  = pb2;
        sB4[bk][bj + 48]  = pb3;
        sB4[bk][bj + 64]  = pb4;
        sB4[bk][bj + 80]  = pb5;
        sB4[bk][bj + 96]  = pb6;
        sB4[bk][bj + 112] = pb7;
        __syncthreads();

        if (k0 + 16 < 256) {                    // prefetch next under compute
            const float* Wn = Wbase + (size_t)(k0 + 16) * 64;
            const float* Bn = Bbase + (size_t)(k0 + 16) * HW;
            pw  = *(const float4*)(Wn);
            pb0 = *(const float4*)(Bn);
            pb1 = *(const float4*)(Bn + 64);
            pb2 = *(const float4*)(Bn + 128);
            pb3 = *(const float4*)(Bn + 192);
            pb4 = *(const float4*)(Bn + 256);
            pb5 = *(const float4*)(Bn + 320);
            pb6 = *(const float4*)(Bn + 384);
            pb7 = *(const float4*)(Bn + 448);
        }

#pragma unroll 2
        for (int k = 0; k < 16; k++) {
            const float4 a0 = sW4[k][(g << 2) + 0];   // uniform -> broadcast
            const float4 a1 = sW4[k][(g << 2) + 1];
            const float4 a2 = sW4[k][(g << 2) + 2];
            const float4 a3 = sW4[k][(g << 2) + 3];
            const float4 b0 = sB4[k][j];
            const float4 b1 = sB4[k][64 + j];
            FR8(u0,  v0,  a0.x) FR8(u1,  v1,  a0.y)
            FR8(u2,  v2,  a0.z) FR8(u3,  v3,  a0.w)
            FR8(u4,  v4,  a1.x) FR8(u5,  v5,  a1.y)
            FR8(u6,  v6,  a1.z) FR8(u7,  v7,  a1.w)
            FR8(u8,  v8,  a2.x) FR8(u9,  v9,  a2.y)
            FR8(u10, v10, a2.z) FR8(u11, v11, a2.w)
            FR8(u12, v12, a3.x) FR8(u13, v13, a3.y)
            FR8(u14, v14, a3.z) FR8(u15, v15, a3.w)
        }
    }

    float* Qo = (br ? Q_s : Q_t) + (size_t)b * 32 * HW;
    float* Ko = (br ? K_s : K_t) + (size_t)b * 32 * HW;
    QK_OUT(u0,  v0,  0)  QK_OUT(u1,  v1,  1)
    QK_OUT(u2,  v2,  2)  QK_OUT(u3,  v3,  3)
    QK_OUT(u4,  v4,  4)  QK_OUT(u5,  v5,  5)
    QK_OUT(u6,  v6,  6)  QK_OUT(u7,  v7,  7)
    QK_OUT(u8,  v8,  8)  QK_OUT(u9,  v9,  9)
    QK_OUT(u10, v10, 10) QK_OUT(u11, v11, 11)
    QK_OUT(u12, v12, 12) QK_OUT(u13, v13, 13)
    QK_OUT(u14, v14, 14) QK_OUT(u15, v15, 15)
}

// ---------------------------------------------------------------------------
// Kernel 2: energy (Qr @ Kr^T over M) + reversed-softmax -> attn (fp32)
// (unchanged this round)
// ---------------------------------------------------------------------------
__global__ __launch_bounds__(256)
void attn_kernel(const float* __restrict__ Q_t, const float* __restrict__ K_t,
                 const float* __restrict__ Q_s, const float* __restrict__ K_s,
                 float* __restrict__ A_t, float* __restrict__ A_s) {
    const int zb = blockIdx.y, br = zb >> 5, b = zb & 31;
    const int M = br ? (HW_S / 8) : (HW_T / 8);          // 512 / 128
    const float* Qb = (br ? Q_s : Q_t) + (size_t)b * 32 * (br ? HW_S : HW_T);
    const float* Kb = (br ? K_s : K_t) + (size_t)b * 32 * (br ? HW_S : HW_T);
    float* attn = (br ? A_s : A_t) + (size_t)b * 65536;
    const int c0 = blockIdx.x * 32;

    __shared__ float sK[256][33];
    __shared__ float sQ[32][33];
    __shared__ float eT[32][260];

    const int tid = threadIdx.x;
    const int dx = tid & 31, cy = tid >> 5;   // thread covers c = cy*4+i, d = dx+32j
    float acc[4][8] = {};

    for (int m0 = 0; m0 < M; m0 += 32) {
        __syncthreads();
        {
            const int rr = tid >> 3;
            const int cc = (tid & 7) << 2;
#pragma unroll
            for (int p = 0; p < 8; p++) {
                const int row = (p << 5) + rr;
                const float4 v = *(const float4*)(Kb + (size_t)row * M + m0 + cc);
                sK[row][cc] = v.x; sK[row][cc + 1] = v.y;
                sK[row][cc + 2] = v.z; sK[row][cc + 3] = v.w;
            }
            const float4 qv = *(const float4*)(Qb + (size_t)(c0 + rr) * M + m0 + cc);
            sQ[rr][cc] = qv.x; sQ[rr][cc + 1] = qv.y;
            sQ[rr][cc + 2] = qv.z; sQ[rr][cc + 3] = qv.w;
        }
        __syncthreads();
#pragma unroll 2
        for (int m = 0; m < 32; m++) {
            float kv[8];
#pragma unroll
            for (int j = 0; j < 8; j++) kv[j] = sK[dx + (j << 5)][m];
#pragma unroll
            for (int i = 0; i < 4; i++) {
                const float qv = sQ[(cy << 2) + i][m];
#pragma unroll
                for (int j = 0; j < 8; j++) acc[i][j] = fmaf(qv, kv[j], acc[i][j]);
            }
        }
    }

#pragma unroll
    for (int i = 0; i < 4; i++)
#pragma unroll
        for (int j = 0; j < 8; j++)
            eT[(cy << 2) + i][dx + (j << 5)] = acc[i][j];
    __syncthreads();

    // softmax: 8 threads per row (consecutive lanes), 32 cols each (stride 8)
    const int r = tid >> 3, s8 = tid & 7;
    float p[32];
    float mn = 3.0e38f;
#pragma unroll
    for (int m = 0; m < 32; m++) { p[m] = eT[r][s8 + (m << 3)]; mn = fminf(mn, p[m]); }
    mn = fminf(mn, __shfl_xor(mn, 1));
    mn = fminf(mn, __shfl_xor(mn, 2));
    mn = fminf(mn, __shfl_xor(mn, 4));
    float sum = 0.f;
#pragma unroll
    for (int m = 0; m < 32; m++) { p[m] = __expf(mn - p[m]); sum += p[m]; }
    sum += __shfl_xor(sum, 1);
    sum += __shfl_xor(sum, 2);
    sum += __shfl_xor(sum, 4);
    const float rinv = 1.0f / sum;
#pragma unroll
    for (int m = 0; m < 32; m++) eT[r][s8 + (m << 3)] = p[m] * rinv;
    __syncthreads();

    for (int idx = tid; idx < 2048; idx += 256) {
        const int row = idx >> 6, c4 = (idx & 63) << 2;
        const float4 v = *(const float4*)&eT[row][c4];
        *(float4*)(attn + (size_t)(c0 + row) * 256 + c4) = v;
    }
}

// ---------------------------------------------------------------------------
// Kernel 3/5: tiled GEMM  C[c][n] = sum_k A[c][k] * B[k][n]
//   256x128 tile, 256 threads, 16x8 micro-tile (unchanged this round —
//   next round reads its counters directly now that qk is off the top).
// ---------------------------------------------------------------------------
#define STA(P, OFF)                                           \
    sAf[(aslot * 4 + 0) * 260 + ar + (OFF)] = P.x;            \
    sAf[(aslot * 4 + 1) * 260 + ar + (OFF)] = P.y;            \
    sAf[(aslot * 4 + 2) * 260 + ar + (OFF)] = P.z;            \
    sAf[(aslot * 4 + 3) * 260 + ar + (OFF)] = P.w;

#define EPI_FIN(AL, AR, CROW) {                               \
    const int c = (CROW);                                     \
    const float bpv = bp[c];                                  \
    const size_t off0 = (size_t)c * N + n0 + (tx << 2);       \
    const float4 z0 = *(const float4*)(Bm + off0);            \
    const float4 z1 = *(const float4*)(Bm + off0 + 64);       \
    float4 o0, o1;                                            \
    o0.x = fmaf(alpha, AL.x + bpv, z0.x);                     \
    o0.y = fmaf(alpha, AL.y + bpv, z0.y);                     \
    o0.z = fmaf(alpha, AL.z + bpv, z0.z);                     \
    o0.w = fmaf(alpha, AL.w + bpv, z0.w);                     \
    o1.x = fmaf(alpha, AR.x + bpv, z1.x);                     \
    o1.y = fmaf(alpha, AR.y + bpv, z1.y);                     \
    o1.z = fmaf(alpha, AR.z + bpv, z1.z);                     \
    o1.w = fmaf(alpha, AR.w + bpv, z1.w);                     \
    *(float4*)(O + off0) = o0;                                \
    *(float4*)(O + off0 + 64) = o1; }

#define EPI_STO(AL, AR, CROW) {                               \
    const int c = (CROW);                                     \
    const size_t off0 = (size_t)c * 256 + n0 + (tx << 2);     \
    *(float4*)(Co + off0) = AL;                               \
    *(float4*)(Co + off0 + 64) = AR; }

template <int FINAL>
__global__ __launch_bounds__(256)
__attribute__((amdgpu_waves_per_eu(2, 2)))
void gemm256(const float* __restrict__ A_t, const float* __restrict__ A_s,
             const float* __restrict__ B_t, const float* __restrict__ B_s,
             float* __restrict__ C_t, float* __restrict__ C_s,
             float* __restrict__ O_t, float* __restrict__ O_s,
             const float* __restrict__ bp_t, const float* __restrict__ bp_s,
             const float* __restrict__ alpha_p, const float* __restrict__ beta_p,
             int N_t, int N_s) {
    const int zb = blockIdx.z, br = zb >> 5, b = zb & 31;
    const int N = br ? N_s : N_t;
    const int n0 = blockIdx.x * 128;
    if (n0 >= N) return;                        // whole-block uniform exit
    const float* A = (br ? A_s : A_t) + (size_t)b * 65536;
    const float* Bm = (br ? B_s : B_t);
    if (FINAL) Bm += (size_t)b * 256 * (size_t)N;

    __shared__ float4 sA4[32][65];              // 256 c per k-row
    __shared__ float4 sB4[32][33];              // 128 n per k-row
    float* sAf = (float*)sA4;

    const int tid = threadIdx.x;
    const int tx = tid & 15, ty = tid >> 4;     // micro-tile coords

    const int ar = tid >> 3, aslot = tid & 7;   // A: c-row ar+32p (p0..7), k=aslot*4..
    const int brow = tid >> 5, bcol = tid & 31; // B: k-row brow+8p (p0..3), n=bcol*4..

    const float* Abase = A + (size_t)ar * 256 + aslot * 4;
    const float* Bbase = Bm + (size_t)brow * N + n0 + bcol * 4;

    float4 cL0{}, cL1{}, cL2{}, cL3{}, cL4{}, cL5{}, cL6{}, cL7{};
    float4 cL8{}, cL9{}, cL10{}, cL11{}, cL12{}, cL13{}, cL14{}, cL15{};
    float4 cR0{}, cR1{}, cR2{}, cR3{}, cR4{}, cR5{}, cR6{}, cR7{};
    float4 cR8{}, cR9{}, cR10{}, cR11{}, cR12{}, cR13{}, cR14{}, cR15{};
    float4 pa0, pa1, pa2, pa3, pa4, pa5, pa6, pa7, pb0, pb1, pb2, pb3;

    pa0 = *(const float4*)(Abase);
    pa1 = *(const float4*)(Abase + 8192);
    pa2 = *(const float4*)(Abase + 16384);
    pa3 = *(const float4*)(Abase + 24576);
    pa4 = *(const float4*)(Abase + 32768);
    pa5 = *(const float4*)(Abase + 40960);
    pa6 = *(const float4*)(Abase + 49152);
    pa7 = *(const float4*)(Abase + 57344);
    pb0 = *(const float4*)(Bbase);
    pb1 = *(const float4*)(Bbase + (size_t)8 * N);
    pb2 = *(const float4*)(Bbase + (size_t)16 * N);
    pb3 = *(const float4*)(Bbase + (size_t)24 * N);

    for (int k0 = 0; k0 < 256; k0 += 32) {
        __syncthreads();
        STA(pa0, 0)   STA(pa1, 32)  STA(pa2, 64)  STA(pa3, 96)
        STA(pa4, 128) STA(pa5, 160) STA(pa6, 192) STA(pa7, 224)
        sB4[brow][bcol]      = pb0;
        sB4[brow + 8][bcol]  = pb1;
        sB4[brow + 16][bcol] = pb2;
        sB4[brow + 24][bcol] = pb3;
        __syncthreads();

        if (k0 + 32 < 256) {
            const int kn = k0 + 32;
            pa0 = *(const float4*)(Abase + kn);
            pa1 = *(const float4*)(Abase + 8192 + kn);
            pa2 = *(const float4*)(Abase + 16384 + kn);
            pa3 = *(const float4*)(Abase + 24576 + kn);
            pa4 = *(const float4*)(Abase + 32768 + kn);
            pa5 = *(const float4*)(Abase + 40960 + kn);
            pa6 = *(const float4*)(Abase + 49152 + kn);
            pa7 = *(const float4*)(Abase + 57344 + kn);
            pb0 = *(const float4*)(Bbase + (size_t)kn * N);
            pb1 = *(const float4*)(Bbase + (size_t)(kn + 8) * N);
            pb2 = *(const float4*)(Bbase + (size_t)(kn + 16) * N);
            pb3 = *(const float4*)(Bbase + (size_t)(kn + 24) * N);
        }

#pragma unroll 4
        for (int k = 0; k < 32; k++) {
            const float4 a0 = sA4[k][ty];
            const float4 a1 = sA4[k][16 + ty];
            const float4 a2 = sA4[k][32 + ty];
            const float4 a3 = sA4[k][48 + ty];
            const float4 b0 = sB4[k][tx];
            const float4 b1 = sB4[k][16 + tx];
            FR8(cL0,  cR0,  a0.x) FR8(cL1,  cR1,  a0.y)
            FR8(cL2,  cR2,  a0.z) FR8(cL3,  cR3,  a0.w)
            FR8(cL4,  cR4,  a1.x) FR8(cL5,  cR5,  a1.y)
            FR8(cL6,  cR6,  a1.z) FR8(cL7,  cR7,  a1.w)
            FR8(cL8,  cR8,  a2.x) FR8(cL9,  cR9,  a2.y)
            FR8(cL10, cR10, a2.z) FR8(cL11, cR11, a2.w)
            FR8(cL12, cR12, a3.x) FR8(cL13, cR13, a3.y)
            FR8(cL14, cR14, a3.z) FR8(cL15, cR15, a3.w)
        }
    }

    if (FINAL) {
        const float alpha = br ? beta_p[0] : alpha_p[0];
        const float* bp = (br ? bp_s : bp_t) + b * 256;
        float* O = (br ? O_s : O_t) + (size_t)b * 256 * (size_t)N;
        EPI_FIN(cL0,  cR0,  (ty << 2) + 0)
        EPI_FIN(cL1,  cR1,  (ty << 2) + 1)
        EPI_FIN(cL2,  cR2,  (ty << 2) + 2)
        EPI_FIN(cL3,  cR3,  (ty << 2) + 3)
        EPI_FIN(cL4,  cR4,  64 + (ty << 2) + 0)
        EPI_FIN(cL5,  cR5,  64 + (ty << 2) + 1)
        EPI_FIN(cL6,  cR6,  64 + (ty << 2) + 2)
        EPI_FIN(cL7,  cR7,  64 + (ty << 2) + 3)
        EPI_FIN(cL8,  cR8,  128 + (ty << 2) + 0)
        EPI_FIN(cL9,  cR9,  128 + (ty << 2) + 1)
        EPI_FIN(cL10, cR10, 128 + (ty << 2) + 2)
        EPI_FIN(cL11, cR11, 128 + (ty << 2) + 3)
        EPI_FIN(cL12, cR12, 192 + (ty << 2) + 0)
        EPI_FIN(cL13, cR13, 192 + (ty << 2) + 1)
        EPI_FIN(cL14, cR14, 192 + (ty << 2) + 2)
        EPI_FIN(cL15, cR15, 192 + (ty << 2) + 3)
    } else {
        float* Co = (br ? C_s : C_t) + (size_t)b * 65536;
        EPI_STO(cL0,  cR0,  (ty << 2) + 0)
        EPI_STO(cL1,  cR1,  (ty << 2) + 1)
        EPI_STO(cL2,  cR2,  (ty << 2) + 2)
        EPI_STO(cL3,  cR3,  (ty << 2) + 3)
        EPI_STO(cL4,  cR4,  64 + (ty << 2) + 0)
        EPI_STO(cL5,  cR5,  64 + (ty << 2) + 1)
        EPI_STO(cL6,  cR6,  64 + (ty << 2) + 2)
        EPI_STO(cL7,  cR7,  64 + (ty << 2) + 3)
        EPI_STO(cL8,  cR8,  128 + (ty << 2) + 0)
        EPI_STO(cL9,  cR9,  128 + (ty << 2) + 1)
        EPI_STO(cL10, cR10, 128 + (ty << 2) + 2)
        EPI_STO(cL11, cR11, 128 + (ty << 2) + 3)
        EPI_STO(cL12, cR12, 192 + (ty << 2) + 0)
        EPI_STO(cL13, cR13, 192 + (ty << 2) + 1)
        EPI_STO(cL14, cR14, 192 + (ty << 2) + 2)
        EPI_STO(cL15, cR15, 192 + (ty << 2) + 3)
    }
}

// ---------------------------------------------------------------------------
// Kernel 4: b'[b][c] = sum_d attn[b][c][d] * vb[d]   (GEMV; vb is tiny)
// ---------------------------------------------------------------------------
__global__ __launch_bounds__(256)
void bprime_kernel(const float* __restrict__ A_t, const float* __restrict__ A_s,
                   const float* __restrict__ vb_t, const float* __restrict__ vb_s,
                   float* __restrict__ bp_t, float* __restrict__ bp_s) {
    const int bx = blockIdx.x, br = bx >> 5, b = bx & 31;
    const float* A = (br ? A_s : A_t) + (size_t)b * 65536;
    const float* vb = br ? vb_s : vb_t;
    float* bp = (br ? bp_s : bp_t) + b * 256;
    __shared__ float svb[256];
    svb[threadIdx.x] = vb[threadIdx.x];
    __syncthreads();
    const int wave = threadIdx.x >> 6, lane = threadIdx.x & 63;
    for (int c = wave; c < 256; c += 4) {
        const float4 a = *(const float4*)(A + (size_t)c * 256 + (lane << 2));
        const int l4 = lane << 2;
        float s = a.x * svb[l4] + a.y * svb[l4 + 1] + a.z * svb[l4 + 2] + a.w * svb[l4 + 3];
#pragma unroll
        for (int off = 32; off > 0; off >>= 1) s += __shfl_down(s, off);
        if (lane == 0) bp[c] = s;
    }
}

// ---------------------------------------------------------------------------
extern "C" void kernel_launch(void* const* d_in, const int* in_sizes, int n_in,
                              void* d_out, int out_size, void* d_ws, size_t ws_size,
                              hipStream_t stream) {
    const float* rgb_t = (const float*)d_in[0];
    const float* rgb_s = (const float*)d_in[1];
    const float* z_t   = (const float*)d_in[2];
    const float* z_s   = (const float*)d_in[3];
    const float* tq_w  = (const float*)d_in[4];
    const float* tq_b  = (const float*)d_in[5];
    const float* tk_w  = (const float*)d_in[6];
    const float* tk_b  = (const float*)d_in[7];
    const float* tv_w  = (const float*)d_in[8];
    const float* tv_b  = (const float*)d_in[9];
    const float* sq_w  = (const float*)d_in[10];
    const float* sq_b  = (const float*)d_in[11];
    const float* sk_w  = (const float*)d_in[12];
    const float* sk_b  = (const float*)d_in[13];
    const float* sv_w  = (const float*)d_in[14];
    const float* sv_b  = (const float*)d_in[15];
    const float* alpha = (const float*)d_in[16];
    const float* beta  = (const float*)d_in[17];

    // workspace layout (fp32).  W' aliases the Q/K region (attn is the last
    // reader of Q/K; gemm256<0> runs after attn_kernel).  Total ~58.9 MB.
    float* ws  = (float*)d_ws;
    float* At  = ws;                       // 32*256*256   attn (t)
    float* As_ = At + 2097152;             // attn (s)
    float* bt  = As_ + 2097152;            // 32*256 b' (t)
    float* bs  = bt + 8192;                // b' (s)
    float* Qt  = bs + 8192;                // 32*32*1024
    float* Kt  = Qt + 1048576;
    float* Qs  = Kt + 1048576;             // 32*32*4096
    float* Ks  = Qs + 4194304;
    float* Wct = Ks + 4194304;             // 256*64 k-major weights (t)
    float* Wcs = Wct + 16384;              // 256*64 (s)
    float* Wt  = Qt;                       // alias: W' (t) over Qt/Kt
    float* Ws_ = Qs;                       // alias: W' (s) over Qs

    float* out_t = (float*)d_out;
    float* out_s = out_t + (size_t)32 * 256 * HW_T;   // 8,388,608 elements

    wprep_kernel<<<dim3(2), 256, 0, stream>>>(tq_w, tk_w, sq_w, sk_w, Wct, Wcs);

    qk_gemm<<<dim3(8, 64), 256, 0, stream>>>(
        rgb_t, rgb_s, Wct, Wcs, tq_b, tk_b, sq_b, sk_b, Qt, Kt, Qs, Ks);

    attn_kernel<<<dim3(8, 64), 256, 0, stream>>>(Qt, Kt, Qs, Ks, At, As_);

    bprime_kernel<<<dim3(64), 256, 0, stream>>>(At, As_, tv_b, sv_b, bt, bs);

    gemm256<0><<<dim3(2, 1, 64), 256, 0, stream>>>(
        At, As_, tv_w, sv_w, Wt, Ws_,
        (float*)nullptr, (float*)nullptr, (const float*)nullptr, (const float*)nullptr,
        (const float*)nullptr, (const float*)nullptr, 256, 256);

    gemm256<1><<<dim3(32, 1, 64), 256, 0, stream>>>(
        Wt, Ws_, z_t, z_s, (float*)nullptr, (float*)nullptr,
        out_t, out_s, bt, bs, alpha, beta, HW_T, HW_S);
}

// Round 7
// 683.764 us; speedup vs baseline: 1.7323x; 1.3044x over previous
//
#include <hip/hip_runtime.h>

#define HW_T 1024
#define HW_S 4096

typedef __attribute__((ext_vector_type(8))) short short8v;   // 8 bf16 = 4 VGPR
typedef __attribute__((ext_vector_type(4))) float f32x4;

__device__ __forceinline__ ushort f2bf(float x) {            // RTN fp32->bf16
    unsigned u = __float_as_uint(x);
    return (ushort)((u + 0x7FFF + ((u >> 16) & 1)) >> 16);
}

// ---------------------------------------------------------------------------
// Kernel 0: wprep — transpose weights to k-major Wc[c][row]: row<32 -> qw,
// row>=32 -> kw.  grid (2): x = branch.
// ---------------------------------------------------------------------------
__global__ __launch_bounds__(256)
void wprep_kernel(const float* __restrict__ qw_t, const float* __restrict__ kw_t,
                  const float* __restrict__ qw_s, const float* __restrict__ kw_s,
                  float* __restrict__ Wc_t, float* __restrict__ Wc_s) {
    const int br = blockIdx.x;
    const float* qw = br ? qw_s : qw_t;
    const float* kw = br ? kw_s : kw_t;
    float* Wc = br ? Wc_s : Wc_t;
    const int c = threadIdx.x;
#pragma unroll 4
    for (int cq = 0; cq < 32; cq++) {
        Wc[c * 64 + cq]      = qw[cq * 256 + c];
        Wc[c * 64 + 32 + cq] = kw[cq * 256 + c];
    }
}

// ---------------------------------------------------------------------------
// Kernel 1: qk_gemm — Q/K 1x1 conv as a 64x512-tile GEMM (unchanged, r6-good).
// ---------------------------------------------------------------------------
#define FR8(AL, AR, AV)                                       \
    AL.x = fmaf(AV, b0.x, AL.x); AL.y = fmaf(AV, b0.y, AL.y); \
    AL.z = fmaf(AV, b0.z, AL.z); AL.w = fmaf(AV, b0.w, AL.w); \
    AR.x = fmaf(AV, b1.x, AR.x); AR.y = fmaf(AV, b1.y, AR.y); \
    AR.z = fmaf(AV, b1.z, AR.z); AR.w = fmaf(AV, b1.w, AR.w);

#define QK_OUT(ACL, ACR, RI) {                                \
    const int row = (g << 4) + (RI);                          \
    const float bv = (row < 32) ? qb[row] : kb[row & 31];     \
    float* Op = ((row < 32) ? Qo : Ko)                        \
                + (size_t)(row & 31) * HW + n0 + (j << 2);    \
    float4 o0, o1;                                            \
    o0.x = ACL.x + bv; o0.y = ACL.y + bv;                     \
    o0.z = ACL.z + bv; o0.w = ACL.w + bv;                     \
    o1.x = ACR.x + bv; o1.y = ACR.y + bv;                     \
    o1.z = ACR.z + bv; o1.w = ACR.w + bv;                     \
    *(float4*)(Op) = o0;                                      \
    *(float4*)(Op + 256) = o1; }

__global__ __launch_bounds__(256)
__attribute__((amdgpu_waves_per_eu(2, 2)))
void qk_gemm(const float* __restrict__ rgb_t, const float* __restrict__ rgb_s,
             const float* __restrict__ Wc_t, const float* __restrict__ Wc_s,
             const float* __restrict__ qb_t, const float* __restrict__ kb_t,
             const float* __restrict__ qb_s, const float* __restrict__ kb_s,
             float* __restrict__ Q_t, float* __restrict__ K_t,
             float* __restrict__ Q_s, float* __restrict__ K_s) {
    const int zb = blockIdx.y, br = zb >> 5, b = zb & 31;
    const int HW = br ? HW_S : HW_T;
    const int n0 = blockIdx.x * 512;
    if (n0 >= HW) return;

    const float* rgb = (br ? rgb_s : rgb_t) + (size_t)b * 256 * HW;
    const float* Wc  = br ? Wc_s : Wc_t;
    const float* qb  = br ? qb_s : qb_t;
    const float* kb  = br ? kb_s : kb_t;

    __shared__ float4 sW4[16][16];
    __shared__ float4 sB4[16][129];

    const int tid = threadIdx.x;
    const int g = tid >> 6;
    const int j = tid & 63;

    const int wk = tid >> 4, wr = tid & 15;
    const int bk = tid >> 4, bj = tid & 15;

    const float* Wbase = Wc + (size_t)wk * 64 + wr * 4;
    const float* Bbase = rgb + (size_t)bk * HW + n0 + bj * 4;

    float4 u0{}, u1{}, u2{}, u3{}, u4{}, u5{}, u6{}, u7{};
    float4 u8{}, u9{}, u10{}, u11{}, u12{}, u13{}, u14{}, u15{};
    float4 v0{}, v1{}, v2{}, v3{}, v4{}, v5{}, v6{}, v7{};
    float4 v8{}, v9{}, v10{}, v11{}, v12{}, v13{}, v14{}, v15{};
    float4 pw, pb0, pb1, pb2, pb3, pb4, pb5, pb6, pb7;

    pw  = *(const float4*)(Wbase);
    pb0 = *(const float4*)(Bbase);
    pb1 = *(const float4*)(Bbase + 64);
    pb2 = *(const float4*)(Bbase + 128);
    pb3 = *(const float4*)(Bbase + 192);
    pb4 = *(const float4*)(Bbase + 256);
    pb5 = *(const float4*)(Bbase + 320);
    pb6 = *(const float4*)(Bbase + 384);
    pb7 = *(const float4*)(Bbase + 448);

    for (int k0 = 0; k0 < 256; k0 += 16) {
        __syncthreads();
        sW4[wk][wr] = pw;
        sB4[bk][bj]       = pb0;
        sB4[bk][bj + 16]  = pb1;
        sB4[bk][bj + 32]  = pb2;
        sB4[bk][bj + 48]  = pb3;
        sB4[bk][bj + 64]  = pb4;
        sB4[bk][bj + 80]  = pb5;
        sB4[bk][bj + 96]  = pb6;
        sB4[bk][bj + 112] = pb7;
        __syncthreads();

        if (k0 + 16 < 256) {
            const float* Wn = Wbase + (size_t)(k0 + 16) * 64;
            const float* Bn = Bbase + (size_t)(k0 + 16) * HW;
            pw  = *(const float4*)(Wn);
            pb0 = *(const float4*)(Bn);
            pb1 = *(const float4*)(Bn + 64);
            pb2 = *(const float4*)(Bn + 128);
            pb3 = *(const float4*)(Bn + 192);
            pb4 = *(const float4*)(Bn + 256);
            pb5 = *(const float4*)(Bn + 320);
            pb6 = *(const float4*)(Bn + 384);
            pb7 = *(const float4*)(Bn + 448);
        }

#pragma unroll 2
        for (int k = 0; k < 16; k++) {
            const float4 a0 = sW4[k][(g << 2) + 0];
            const float4 a1 = sW4[k][(g << 2) + 1];
            const float4 a2 = sW4[k][(g << 2) + 2];
            const float4 a3 = sW4[k][(g << 2) + 3];
            const float4 b0 = sB4[k][j];
            const float4 b1 = sB4[k][64 + j];
            FR8(u0,  v0,  a0.x) FR8(u1,  v1,  a0.y)
            FR8(u2,  v2,  a0.z) FR8(u3,  v3,  a0.w)
            FR8(u4,  v4,  a1.x) FR8(u5,  v5,  a1.y)
            FR8(u6,  v6,  a1.z) FR8(u7,  v7,  a1.w)
            FR8(u8,  v8,  a2.x) FR8(u9,  v9,  a2.y)
            FR8(u10, v10, a2.z) FR8(u11, v11, a2.w)
            FR8(u12, v12, a3.x) FR8(u13, v13, a3.y)
            FR8(u14, v14, a3.z) FR8(u15, v15, a3.w)
        }
    }

    float* Qo = (br ? Q_s : Q_t) + (size_t)b * 32 * HW;
    float* Ko = (br ? K_s : K_t) + (size_t)b * 32 * HW;
    QK_OUT(u0,  v0,  0)  QK_OUT(u1,  v1,  1)
    QK_OUT(u2,  v2,  2)  QK_OUT(u3,  v3,  3)
    QK_OUT(u4,  v4,  4)  QK_OUT(u5,  v5,  5)
    QK_OUT(u6,  v6,  6)  QK_OUT(u7,  v7,  7)
    QK_OUT(u8,  v8,  8)  QK_OUT(u9,  v9,  9)
    QK_OUT(u10, v10, 10) QK_OUT(u11, v11, 11)
    QK_OUT(u12, v12, 12) QK_OUT(u13, v13, 13)
    QK_OUT(u14, v14, 14) QK_OUT(u15, v15, 15)
}

// ---------------------------------------------------------------------------
// Kernel 2: energy + reversed-softmax -> attn (fp32)  (unchanged)
// ---------------------------------------------------------------------------
__global__ __launch_bounds__(256)
void attn_kernel(const float* __restrict__ Q_t, const float* __restrict__ K_t,
                 const float* __restrict__ Q_s, const float* __restrict__ K_s,
                 float* __restrict__ A_t, float* __restrict__ A_s) {
    const int zb = blockIdx.y, br = zb >> 5, b = zb & 31;
    const int M = br ? (HW_S / 8) : (HW_T / 8);
    const float* Qb = (br ? Q_s : Q_t) + (size_t)b * 32 * (br ? HW_S : HW_T);
    const float* Kb = (br ? K_s : K_t) + (size_t)b * 32 * (br ? HW_S : HW_T);
    float* attn = (br ? A_s : A_t) + (size_t)b * 65536;
    const int c0 = blockIdx.x * 32;

    __shared__ float sK[256][33];
    __shared__ float sQ[32][33];
    __shared__ float eT[32][260];

    const int tid = threadIdx.x;
    const int dx = tid & 31, cy = tid >> 5;
    float acc[4][8] = {};

    for (int m0 = 0; m0 < M; m0 += 32) {
        __syncthreads();
        {
            const int rr = tid >> 3;
            const int cc = (tid & 7) << 2;
#pragma unroll
            for (int p = 0; p < 8; p++) {
                const int row = (p << 5) + rr;
                const float4 v = *(const float4*)(Kb + (size_t)row * M + m0 + cc);
                sK[row][cc] = v.x; sK[row][cc + 1] = v.y;
                sK[row][cc + 2] = v.z; sK[row][cc + 3] = v.w;
            }
            const float4 qv = *(const float4*)(Qb + (size_t)(c0 + rr) * M + m0 + cc);
            sQ[rr][cc] = qv.x; sQ[rr][cc + 1] = qv.y;
            sQ[rr][cc + 2] = qv.z; sQ[rr][cc + 3] = qv.w;
        }
        __syncthreads();
#pragma unroll 2
        for (int m = 0; m < 32; m++) {
            float kv[8];
#pragma unroll
            for (int j = 0; j < 8; j++) kv[j] = sK[dx + (j << 5)][m];
#pragma unroll
            for (int i = 0; i < 4; i++) {
                const float qv = sQ[(cy << 2) + i][m];
#pragma unroll
                for (int j = 0; j < 8; j++) acc[i][j] = fmaf(qv, kv[j], acc[i][j]);
            }
        }
    }

#pragma unroll
    for (int i = 0; i < 4; i++)
#pragma unroll
        for (int j = 0; j < 8; j++)
            eT[(cy << 2) + i][dx + (j << 5)] = acc[i][j];
    __syncthreads();

    const int r = tid >> 3, s8 = tid & 7;
    float p[32];
    float mn = 3.0e38f;
#pragma unroll
    for (int m = 0; m < 32; m++) { p[m] = eT[r][s8 + (m << 3)]; mn = fminf(mn, p[m]); }
    mn = fminf(mn, __shfl_xor(mn, 1));
    mn = fminf(mn, __shfl_xor(mn, 2));
    mn = fminf(mn, __shfl_xor(mn, 4));
    float sum = 0.f;
#pragma unroll
    for (int m = 0; m < 32; m++) { p[m] = __expf(mn - p[m]); sum += p[m]; }
    sum += __shfl_xor(sum, 1);
    sum += __shfl_xor(sum, 2);
    sum += __shfl_xor(sum, 4);
    const float rinv = 1.0f / sum;
#pragma unroll
    for (int m = 0; m < 32; m++) eT[r][s8 + (m << 3)] = p[m] * rinv;
    __syncthreads();

    for (int idx = tid; idx < 2048; idx += 256) {
        const int row = idx >> 6, c4 = (idx & 63) << 2;
        const float4 v = *(const float4*)&eT[row][c4];
        *(float4*)(attn + (size_t)(c0 + row) * 256 + c4) = v;
    }
}

// ---------------------------------------------------------------------------
// Kernel 3: wgemm — W' = attn @ Vw (fp32 compute, r6 gemm256<0> structure),
// epilogue converts to bf16 (RTN) for the MFMA consumer.  grid (2, 1, 64).
// ---------------------------------------------------------------------------
#define STA(P, OFF)                                           \
    sAf[(aslot * 4 + 0) * 260 + ar + (OFF)] = P.x;            \
    sAf[(aslot * 4 + 1) * 260 + ar + (OFF)] = P.y;            \
    sAf[(aslot * 4 + 2) * 260 + ar + (OFF)] = P.z;            \
    sAf[(aslot * 4 + 3) * 260 + ar + (OFF)] = P.w;

#define EPI_STO(AL, AR, CROW) {                               \
    const int c = (CROW);                                     \
    const size_t off0 = (size_t)c * 256 + n0 + (tx << 2);     \
    ushort4 h0, h1;                                           \
    h0.x = f2bf(AL.x); h0.y = f2bf(AL.y);                     \
    h0.z = f2bf(AL.z); h0.w = f2bf(AL.w);                     \
    h1.x = f2bf(AR.x); h1.y = f2bf(AR.y);                     \
    h1.z = f2bf(AR.z); h1.w = f2bf(AR.w);                     \
    *(ushort4*)(Co + off0) = h0;                              \
    *(ushort4*)(Co + off0 + 64) = h1; }

__global__ __launch_bounds__(256)
__attribute__((amdgpu_waves_per_eu(2, 2)))
void wgemm(const float* __restrict__ A_t, const float* __restrict__ A_s,
           const float* __restrict__ B_t, const float* __restrict__ B_s,
           ushort* __restrict__ W_t, ushort* __restrict__ W_s) {
    const int zb = blockIdx.z, br = zb >> 5, b = zb & 31;
    const int N = 256;
    const int n0 = blockIdx.x * 128;
    const float* A = (br ? A_s : A_t) + (size_t)b * 65536;
    const float* Bm = (br ? B_s : B_t);

    __shared__ float4 sA4[32][65];
    __shared__ float4 sB4[32][33];
    float* sAf = (float*)sA4;

    const int tid = threadIdx.x;
    const int tx = tid & 15, ty = tid >> 4;

    const int ar = tid >> 3, aslot = tid & 7;
    const int brow = tid >> 5, bcol = tid & 31;

    const float* Abase = A + (size_t)ar * 256 + aslot * 4;
    const float* Bbase = Bm + (size_t)brow * N + n0 + bcol * 4;

    float4 cL0{}, cL1{}, cL2{}, cL3{}, cL4{}, cL5{}, cL6{}, cL7{};
    float4 cL8{}, cL9{}, cL10{}, cL11{}, cL12{}, cL13{}, cL14{}, cL15{};
    float4 cR0{}, cR1{}, cR2{}, cR3{}, cR4{}, cR5{}, cR6{}, cR7{};
    float4 cR8{}, cR9{}, cR10{}, cR11{}, cR12{}, cR13{}, cR14{}, cR15{};
    float4 pa0, pa1, pa2, pa3, pa4, pa5, pa6, pa7, pb0, pb1, pb2, pb3;

    pa0 = *(const float4*)(Abase);
    pa1 = *(const float4*)(Abase + 8192);
    pa2 = *(const float4*)(Abase + 16384);
    pa3 = *(const float4*)(Abase + 24576);
    pa4 = *(const float4*)(Abase + 32768);
    pa5 = *(const float4*)(Abase + 40960);
    pa6 = *(const float4*)(Abase + 49152);
    pa7 = *(const float4*)(Abase + 57344);
    pb0 = *(const float4*)(Bbase);
    pb1 = *(const float4*)(Bbase + (size_t)8 * N);
    pb2 = *(const float4*)(Bbase + (size_t)16 * N);
    pb3 = *(const float4*)(Bbase + (size_t)24 * N);

    for (int k0 = 0; k0 < 256; k0 += 32) {
        __syncthreads();
        STA(pa0, 0)   STA(pa1, 32)  STA(pa2, 64)  STA(pa3, 96)
        STA(pa4, 128) STA(pa5, 160) STA(pa6, 192) STA(pa7, 224)
        sB4[brow][bcol]      = pb0;
        sB4[brow + 8][bcol]  = pb1;
        sB4[brow + 16][bcol] = pb2;
        sB4[brow + 24][bcol] = pb3;
        __syncthreads();

        if (k0 + 32 < 256) {
            const int kn = k0 + 32;
            pa0 = *(const float4*)(Abase + kn);
            pa1 = *(const float4*)(Abase + 8192 + kn);
            pa2 = *(const float4*)(Abase + 16384 + kn);
            pa3 = *(const float4*)(Abase + 24576 + kn);
            pa4 = *(const float4*)(Abase + 32768 + kn);
            pa5 = *(const float4*)(Abase + 40960 + kn);
            pa6 = *(const float4*)(Abase + 49152 + kn);
            pa7 = *(const float4*)(Abase + 57344 + kn);
            pb0 = *(const float4*)(Bbase + (size_t)kn * N);
            pb1 = *(const float4*)(Bbase + (size_t)(kn + 8) * N);
            pb2 = *(const float4*)(Bbase + (size_t)(kn + 16) * N);
            pb3 = *(const float4*)(Bbase + (size_t)(kn + 24) * N);
        }

#pragma unroll 4
        for (int k = 0; k < 32; k++) {
            const float4 a0 = sA4[k][ty];
            const float4 a1 = sA4[k][16 + ty];
            const float4 a2 = sA4[k][32 + ty];
            const float4 a3 = sA4[k][48 + ty];
            const float4 b0 = sB4[k][tx];
            const float4 b1 = sB4[k][16 + tx];
            FR8(cL0,  cR0,  a0.x) FR8(cL1,  cR1,  a0.y)
            FR8(cL2,  cR2,  a0.z) FR8(cL3,  cR3,  a0.w)
            FR8(cL4,  cR4,  a1.x) FR8(cL5,  cR5,  a1.y)
            FR8(cL6,  cR6,  a1.z) FR8(cL7,  cR7,  a1.w)
            FR8(cL8,  cR8,  a2.x) FR8(cL9,  cR9,  a2.y)
            FR8(cL10, cR10, a2.z) FR8(cL11, cR11, a2.w)
            FR8(cL12, cR12, a3.x) FR8(cL13, cR13, a3.y)
            FR8(cL14, cR14, a3.z) FR8(cL15, cR15, a3.w)
        }
    }

    ushort* Co = (br ? W_s : W_t) + (size_t)b * 65536;
    EPI_STO(cL0,  cR0,  (ty << 2) + 0)
    EPI_STO(cL1,  cR1,  (ty << 2) + 1)
    EPI_STO(cL2,  cR2,  (ty << 2) + 2)
    EPI_STO(cL3,  cR3,  (ty << 2) + 3)
    EPI_STO(cL4,  cR4,  64 + (ty << 2) + 0)
    EPI_STO(cL5,  cR5,  64 + (ty << 2) + 1)
    EPI_STO(cL6,  cR6,  64 + (ty << 2) + 2)
    EPI_STO(cL7,  cR7,  64 + (ty << 2) + 3)
    EPI_STO(cL8,  cR8,  128 + (ty << 2) + 0)
    EPI_STO(cL9,  cR9,  128 + (ty << 2) + 1)
    EPI_STO(cL10, cR10, 128 + (ty << 2) + 2)
    EPI_STO(cL11, cR11, 128 + (ty << 2) + 3)
    EPI_STO(cL12, cR12, 192 + (ty << 2) + 0)
    EPI_STO(cL13, cR13, 192 + (ty << 2) + 1)
    EPI_STO(cL14, cR14, 192 + (ty << 2) + 2)
    EPI_STO(cL15, cR15, 192 + (ty << 2) + 3)
}

// ---------------------------------------------------------------------------
// Kernel 4: b' GEMV (unchanged)
// ---------------------------------------------------------------------------
__global__ __launch_bounds__(256)
void bprime_kernel(const float* __restrict__ A_t, const float* __restrict__ A_s,
                   const float* __restrict__ vb_t, const float* __restrict__ vb_s,
                   float* __restrict__ bp_t, float* __restrict__ bp_s) {
    const int bx = blockIdx.x, br = bx >> 5, b = bx & 31;
    const float* A = (br ? A_s : A_t) + (size_t)b * 65536;
    const float* vb = br ? vb_s : vb_t;
    float* bp = (br ? bp_s : bp_t) + b * 256;
    __shared__ float svb[256];
    svb[threadIdx.x] = vb[threadIdx.x];
    __syncthreads();
    const int wave = threadIdx.x >> 6, lane = threadIdx.x & 63;
    for (int c = wave; c < 256; c += 4) {
        const float4 a = *(const float4*)(A + (size_t)c * 256 + (lane << 2));
        const int l4 = lane << 2;
        float s = a.x * svb[l4] + a.y * svb[l4 + 1] + a.z * svb[l4 + 2] + a.w * svb[l4 + 3];
#pragma unroll
        for (int off = 32; off > 0; off >>= 1) s += __shfl_down(s, off);
        if (lane == 0) bp[c] = s;
    }
}

// ---------------------------------------------------------------------------
// Kernel 5: vz_mfma — out = alpha*(W'@z + b') + z via bf16 MFMA 16x16x32.
//   Tile 256(M) x 64(N), K=256 in steps of 32.  4 waves: wave w owns rows
//   w*64..w*64+63, all 64 n.  Fragment layouts (gfx950, guide-verified):
//   A: lane l -> A[m=l&15][k=(l>>4)*8+j]; B: lane l -> B[k=(l>>4)*8+j][n=l&15];
//   D: col=lane&15, row=(lane>>4)*4+reg.
//   LDS rows 40 ushorts (80 B = 5x16B): b128 frags aligned, <=2-way conflicts.
//   z staged via 8 scalar fp32 loads/thread (coalesced 256B/wave) -> RTN bf16
//   -> u16 scatter (consecutive lanes = consecutive rows -> 2-way max).
// grid (64, 64): x -> n-block (t exits x>=16), y -> (branch, batch).
// ---------------------------------------------------------------------------
#define MF(CC, AF, BF) CC = __builtin_amdgcn_mfma_f32_16x16x32_bf16(AF, BF, CC, 0, 0, 0);

#define EPO(CC, R, C) {                                                     \
    const int cg = (w << 6) + ((R) << 4) + (lk << 2);                       \
    const size_t nn = (size_t)(n0 + ((C) << 4) + lr);                       \
    const size_t o0 = (size_t)(cg + 0) * N + nn;                            \
    const size_t o1 = (size_t)(cg + 1) * N + nn;                            \
    const size_t o2 = (size_t)(cg + 2) * N + nn;                            \
    const size_t o3 = (size_t)(cg + 3) * N + nn;                            \
    O[o0] = fmaf(alpha, CC.x + bp[cg + 0], Z[o0]);                          \
    O[o1] = fmaf(alpha, CC.y + bp[cg + 1], Z[o1]);                          \
    O[o2] = fmaf(alpha, CC.z + bp[cg + 2], Z[o2]);                          \
    O[o3] = fmaf(alpha, CC.w + bp[cg + 3], Z[o3]); }

__global__ __launch_bounds__(256)
__attribute__((amdgpu_waves_per_eu(2, 3)))
void vz_mfma(const ushort* __restrict__ W_t, const ushort* __restrict__ W_s,
             const float* __restrict__ z_t, const float* __restrict__ z_s,
             float* __restrict__ O_t, float* __restrict__ O_s,
             const float* __restrict__ bp_t, const float* __restrict__ bp_s,
             const float* __restrict__ alpha_p, const float* __restrict__ beta_p,
             int N_t, int N_s) {
    const int zb = blockIdx.y, br = zb >> 5, b = zb & 31;
    const int N = br ? N_s : N_t;
    const int n0 = blockIdx.x * 64;
    if (n0 >= N) return;
    const ushort* Wb = (br ? W_s : W_t) + (size_t)b * 65536;
    const float* Z = (br ? z_s : z_t) + (size_t)b * 256 * (size_t)N;

    __shared__ ushort sA[256 * 40];             // [m][40] rows, 20 KiB
    __shared__ ushort sB[64 * 40];              // [n][40] rows,  5 KiB

    const int tid = threadIdx.x;
    const int w = tid >> 6, l = tid & 63;
    const int lr = l & 15, lk = l >> 4;

    const int am = tid >> 2, aks = tid & 3;     // A stage: rows am+64p, slot aks
    const int zn = tid & 63, zw = tid >> 6;     // z stage: col zn, k = zw+4p

    const ushort* Abase = Wb + (size_t)am * 256 + aks * 8;
    const float*  Bbase = Z + (size_t)zw * N + n0 + zn;

    f32x4 c00{}, c01{}, c02{}, c03{};
    f32x4 c10{}, c11{}, c12{}, c13{};
    f32x4 c20{}, c21{}, c22{}, c23{};
    f32x4 c30{}, c31{}, c32{}, c33{};

    uint4 qa0, qa1, qa2, qa3;
    float qz0, qz1, qz2, qz3, qz4, qz5, qz6, qz7;

    qa0 = *(const uint4*)(Abase);
    qa1 = *(const uint4*)(Abase + 16384);
    qa2 = *(const uint4*)(Abase + 32768);
    qa3 = *(const uint4*)(Abase + 49152);
    qz0 = Bbase[0];
    qz1 = Bbase[(size_t)4 * N];
    qz2 = Bbase[(size_t)8 * N];
    qz3 = Bbase[(size_t)12 * N];
    qz4 = Bbase[(size_t)16 * N];
    qz5 = Bbase[(size_t)20 * N];
    qz6 = Bbase[(size_t)24 * N];
    qz7 = Bbase[(size_t)28 * N];

    const int sa0 = am * 40 + aks * 8;
    const int sb0 = zn * 40 + zw;
    const int ra = (w * 64 + lr) * 40 + lk * 8;
    const int rb = lr * 40 + lk * 8;

    for (int k0 = 0; k0 < 256; k0 += 32) {
        __syncthreads();
        *(uint4*)&sA[sa0]            = qa0;
        *(uint4*)&sA[sa0 + 64 * 40]  = qa1;
        *(uint4*)&sA[sa0 + 128 * 40] = qa2;
        *(uint4*)&sA[sa0 + 192 * 40] = qa3;
        sB[sb0]      = f2bf(qz0);
        sB[sb0 + 4]  = f2bf(qz1);
        sB[sb0 + 8]  = f2bf(qz2);
        sB[sb0 + 12] = f2bf(qz3);
        sB[sb0 + 16] = f2bf(qz4);
        sB[sb0 + 20] = f2bf(qz5);
        sB[sb0 + 24] = f2bf(qz6);
        sB[sb0 + 28] = f2bf(qz7);
        __syncthreads();

        if (k0 + 32 < 256) {
            const int kn = k0 + 32;
            qa0 = *(const uint4*)(Abase + kn);
            qa1 = *(const uint4*)(Abase + 16384 + kn);
            qa2 = *(const uint4*)(Abase + 32768 + kn);
            qa3 = *(const uint4*)(Abase + 49152 + kn);
            const float* Bn = Bbase + (size_t)kn * N;
            qz0 = Bn[0];
            qz1 = Bn[(size_t)4 * N];
            qz2 = Bn[(size_t)8 * N];
            qz3 = Bn[(size_t)12 * N];
            qz4 = Bn[(size_t)16 * N];
            qz5 = Bn[(size_t)20 * N];
            qz6 = Bn[(size_t)24 * N];
            qz7 = Bn[(size_t)28 * N];
        }

        const short8v a0 = *(const short8v*)&sA[ra];
        const short8v a1 = *(const short8v*)&sA[ra + 16 * 40];
        const short8v a2 = *(const short8v*)&sA[ra + 32 * 40];
        const short8v a3 = *(const short8v*)&sA[ra + 48 * 40];
        const short8v b0 = *(const short8v*)&sB[rb];
        const short8v b1 = *(const short8v*)&sB[rb + 16 * 40];
        const short8v b2 = *(const short8v*)&sB[rb + 32 * 40];
        const short8v b3 = *(const short8v*)&sB[rb + 48 * 40];

        MF(c00, a0, b0) MF(c01, a0, b1) MF(c02, a0, b2) MF(c03, a0, b3)
        MF(c10, a1, b0) MF(c11, a1, b1) MF(c12, a1, b2) MF(c13, a1, b3)
        MF(c20, a2, b0) MF(c21, a2, b1) MF(c22, a2, b2) MF(c23, a2, b3)
        MF(c30, a3, b0) MF(c31, a3, b1) MF(c32, a3, b2) MF(c33, a3, b3)
    }

    const float alpha = br ? beta_p[0] : alpha_p[0];
    const float* bp = (br ? bp_s : bp_t) + b * 256;
    float* O = (br ? O_s : O_t) + (size_t)b * 256 * (size_t)N;

    EPO(c00, 0, 0) EPO(c01, 0, 1) EPO(c02, 0, 2) EPO(c03, 0, 3)
    EPO(c10, 1, 0) EPO(c11, 1, 1) EPO(c12, 1, 2) EPO(c13, 1, 3)
    EPO(c20, 2, 0) EPO(c21, 2, 1) EPO(c22, 2, 2) EPO(c23, 2, 3)
    EPO(c30, 3, 0) EPO(c31, 3, 1) EPO(c32, 3, 2) EPO(c33, 3, 3)
}

// ---------------------------------------------------------------------------
extern "C" void kernel_launch(void* const* d_in, const int* in_sizes, int n_in,
                              void* d_out, int out_size, void* d_ws, size_t ws_size,
                              hipStream_t stream) {
    const float* rgb_t = (const float*)d_in[0];
    const float* rgb_s = (const float*)d_in[1];
    const float* z_t   = (const float*)d_in[2];
    const float* z_s   = (const float*)d_in[3];
    const float* tq_w  = (const float*)d_in[4];
    const float* tq_b  = (const float*)d_in[5];
    const float* tk_w  = (const float*)d_in[6];
    const float* tk_b  = (const float*)d_in[7];
    const float* tv_w  = (const float*)d_in[8];
    const float* tv_b  = (const float*)d_in[9];
    const float* sq_w  = (const float*)d_in[10];
    const float* sq_b  = (const float*)d_in[11];
    const float* sk_w  = (const float*)d_in[12];
    const float* sk_b  = (const float*)d_in[13];
    const float* sv_w  = (const float*)d_in[14];
    const float* sv_b  = (const float*)d_in[15];
    const float* alpha = (const float*)d_in[16];
    const float* beta  = (const float*)d_in[17];

    // workspace layout (fp32).  W'(bf16) aliases the Q/K region (attn is the
    // last reader of Q/K; wgemm runs after attn_kernel).
    float* ws  = (float*)d_ws;
    float* At  = ws;                       // 32*256*256   attn (t)
    float* As_ = At + 2097152;             // attn (s)
    float* bt  = As_ + 2097152;            // 32*256 b' (t)
    float* bs  = bt + 8192;                // b' (s)
    float* Qt  = bs + 8192;                // 32*32*1024
    float* Kt  = Qt + 1048576;
    float* Qs  = Kt + 1048576;             // 32*32*4096
    float* Ks  = Qs + 4194304;
    float* Wct = Ks + 4194304;             // 256*64 k-major weights (t)
    float* Wcs = Wct + 16384;              // 256*64 (s)
    ushort* Wbt = (ushort*)Qt;             // alias: W' bf16 (t), 4 MB over Qt
    ushort* Wbs = (ushort*)Qs;             // alias: W' bf16 (s), 4 MB over Qs

    float* out_t = (float*)d_out;
    float* out_s = out_t + (size_t)32 * 256 * HW_T;

    wprep_kernel<<<dim3(2), 256, 0, stream>>>(tq_w, tk_w, sq_w, sk_w, Wct, Wcs);

    qk_gemm<<<dim3(8, 64), 256, 0, stream>>>(
        rgb_t, rgb_s, Wct, Wcs, tq_b, tk_b, sq_b, sk_b, Qt, Kt, Qs, Ks);

    attn_kernel<<<dim3(8, 64), 256, 0, stream>>>(Qt, Kt, Qs, Ks, At, As_);

    bprime_kernel<<<dim3(64), 256, 0, stream>>>(At, As_, tv_b, sv_b, bt, bs);

    wgemm<<<dim3(2, 1, 64), 256, 0, stream>>>(At, As_, tv_w, sv_w, Wbt, Wbs);

    vz_mfma<<<dim3(64, 64), 256, 0, stream>>>(
        Wbt, Wbs, z_t, z_s, out_t, out_s, bt, bs, alpha, beta, HW_T, HW_S);
}

// Round 8
// 669.629 us; speedup vs baseline: 1.7689x; 1.0211x over previous
//
#include <hip/hip_runtime.h>

#define HW_T 1024
#define HW_S 4096

typedef __attribute__((ext_vector_type(8))) short short8v;   // 8 bf16 = 4 VGPR
typedef __attribute__((ext_vector_type(4))) float f32x4;

__device__ __forceinline__ ushort f2bf(float x) {            // RTN fp32->bf16
    unsigned u = __float_as_uint(x);
    return (ushort)((u + 0x7FFF + ((u >> 16) & 1)) >> 16);
}
__device__ __forceinline__ unsigned pk2(float lo, float hi) {
    return (unsigned)f2bf(lo) | ((unsigned)f2bf(hi) << 16);
}

// ---------------------------------------------------------------------------
// Kernel 0: wprep — transpose weights to k-major Wc[c][row]: row<32 -> qw,
// row>=32 -> kw.  grid (2): x = branch.
// ---------------------------------------------------------------------------
__global__ __launch_bounds__(256)
void wprep_kernel(const float* __restrict__ qw_t, const float* __restrict__ kw_t,
                  const float* __restrict__ qw_s, const float* __restrict__ kw_s,
                  float* __restrict__ Wc_t, float* __restrict__ Wc_s) {
    const int br = blockIdx.x;
    const float* qw = br ? qw_s : qw_t;
    const float* kw = br ? kw_s : kw_t;
    float* Wc = br ? Wc_s : Wc_t;
    const int c = threadIdx.x;
#pragma unroll 4
    for (int cq = 0; cq < 32; cq++) {
        Wc[c * 64 + cq]      = qw[cq * 256 + c];
        Wc[c * 64 + 32 + cq] = kw[cq * 256 + c];
    }
}

// ---------------------------------------------------------------------------
// Kernel 1: qk_gemm — Q/K 1x1 conv as a 64x512-tile GEMM (unchanged, r6-good).
// ---------------------------------------------------------------------------
#define FR8(AL, AR, AV)                                       \
    AL.x = fmaf(AV, b0.x, AL.x); AL.y = fmaf(AV, b0.y, AL.y); \
    AL.z = fmaf(AV, b0.z, AL.z); AL.w = fmaf(AV, b0.w, AL.w); \
    AR.x = fmaf(AV, b1.x, AR.x); AR.y = fmaf(AV, b1.y, AR.y); \
    AR.z = fmaf(AV, b1.z, AR.z); AR.w = fmaf(AV, b1.w, AR.w);

#define QK_OUT(ACL, ACR, RI) {                                \
    const int row = (g << 4) + (RI);                          \
    const float bv = (row < 32) ? qb[row] : kb[row & 31];     \
    float* Op = ((row < 32) ? Qo : Ko)                        \
                + (size_t)(row & 31) * HW + n0 + (j << 2);    \
    float4 o0, o1;                                            \
    o0.x = ACL.x + bv; o0.y = ACL.y + bv;                     \
    o0.z = ACL.z + bv; o0.w = ACL.w + bv;                     \
    o1.x = ACR.x + bv; o1.y = ACR.y + bv;                     \
    o1.z = ACR.z + bv; o1.w = ACR.w + bv;                     \
    *(float4*)(Op) = o0;                                      \
    *(float4*)(Op + 256) = o1; }

__global__ __launch_bounds__(256)
__attribute__((amdgpu_waves_per_eu(2, 2)))
void qk_gemm(const float* __restrict__ rgb_t, const float* __restrict__ rgb_s,
             const float* __restrict__ Wc_t, const float* __restrict__ Wc_s,
             const float* __restrict__ qb_t, const float* __restrict__ kb_t,
             const float* __restrict__ qb_s, const float* __restrict__ kb_s,
             float* __restrict__ Q_t, float* __restrict__ K_t,
             float* __restrict__ Q_s, float* __restrict__ K_s) {
    const int zb = blockIdx.y, br = zb >> 5, b = zb & 31;
    const int HW = br ? HW_S : HW_T;
    const int n0 = blockIdx.x * 512;
    if (n0 >= HW) return;

    const float* rgb = (br ? rgb_s : rgb_t) + (size_t)b * 256 * HW;
    const float* Wc  = br ? Wc_s : Wc_t;
    const float* qb  = br ? qb_s : qb_t;
    const float* kb  = br ? kb_s : kb_t;

    __shared__ float4 sW4[16][16];
    __shared__ float4 sB4[16][129];

    const int tid = threadIdx.x;
    const int g = tid >> 6;
    const int j = tid & 63;

    const int wk = tid >> 4, wr = tid & 15;
    const int bk = tid >> 4, bj = tid & 15;

    const float* Wbase = Wc + (size_t)wk * 64 + wr * 4;
    const float* Bbase = rgb + (size_t)bk * HW + n0 + bj * 4;

    float4 u0{}, u1{}, u2{}, u3{}, u4{}, u5{}, u6{}, u7{};
    float4 u8{}, u9{}, u10{}, u11{}, u12{}, u13{}, u14{}, u15{};
    float4 v0{}, v1{}, v2{}, v3{}, v4{}, v5{}, v6{}, v7{};
    float4 v8{}, v9{}, v10{}, v11{}, v12{}, v13{}, v14{}, v15{};
    float4 pw, pb0, pb1, pb2, pb3, pb4, pb5, pb6, pb7;

    pw  = *(const float4*)(Wbase);
    pb0 = *(const float4*)(Bbase);
    pb1 = *(const float4*)(Bbase + 64);
    pb2 = *(const float4*)(Bbase + 128);
    pb3 = *(const float4*)(Bbase + 192);
    pb4 = *(const float4*)(Bbase + 256);
    pb5 = *(const float4*)(Bbase + 320);
    pb6 = *(const float4*)(Bbase + 384);
    pb7 = *(const float4*)(Bbase + 448);

    for (int k0 = 0; k0 < 256; k0 += 16) {
        __syncthreads();
        sW4[wk][wr] = pw;
        sB4[bk][bj]       = pb0;
        sB4[bk][bj + 16]  = pb1;
        sB4[bk][bj + 32]  = pb2;
        sB4[bk][bj + 48]  = pb3;
        sB4[bk][bj + 64]  = pb4;
        sB4[bk][bj + 80]  = pb5;
        sB4[bk][bj + 96]  = pb6;
        sB4[bk][bj + 112] = pb7;
        __syncthreads();

        if (k0 + 16 < 256) {
            const float* Wn = Wbase + (size_t)(k0 + 16) * 64;
            const float* Bn = Bbase + (size_t)(k0 + 16) * HW;
            pw  = *(const float4*)(Wn);
            pb0 = *(const float4*)(Bn);
            pb1 = *(const float4*)(Bn + 64);
            pb2 = *(const float4*)(Bn + 128);
            pb3 = *(const float4*)(Bn + 192);
            pb4 = *(const float4*)(Bn + 256);
            pb5 = *(const float4*)(Bn + 320);
            pb6 = *(const float4*)(Bn + 384);
            pb7 = *(const float4*)(Bn + 448);
        }

#pragma unroll 2
        for (int k = 0; k < 16; k++) {
            const float4 a0 = sW4[k][(g << 2) + 0];
            const float4 a1 = sW4[k][(g << 2) + 1];
            const float4 a2 = sW4[k][(g << 2) + 2];
            const float4 a3 = sW4[k][(g << 2) + 3];
            const float4 b0 = sB4[k][j];
            const float4 b1 = sB4[k][64 + j];
            FR8(u0,  v0,  a0.x) FR8(u1,  v1,  a0.y)
            FR8(u2,  v2,  a0.z) FR8(u3,  v3,  a0.w)
            FR8(u4,  v4,  a1.x) FR8(u5,  v5,  a1.y)
            FR8(u6,  v6,  a1.z) FR8(u7,  v7,  a1.w)
            FR8(u8,  v8,  a2.x) FR8(u9,  v9,  a2.y)
            FR8(u10, v10, a2.z) FR8(u11, v11, a2.w)
            FR8(u12, v12, a3.x) FR8(u13, v13, a3.y)
            FR8(u14, v14, a3.z) FR8(u15, v15, a3.w)
        }
    }

    float* Qo = (br ? Q_s : Q_t) + (size_t)b * 32 * HW;
    float* Ko = (br ? K_s : K_t) + (size_t)b * 32 * HW;
    QK_OUT(u0,  v0,  0)  QK_OUT(u1,  v1,  1)
    QK_OUT(u2,  v2,  2)  QK_OUT(u3,  v3,  3)
    QK_OUT(u4,  v4,  4)  QK_OUT(u5,  v5,  5)
    QK_OUT(u6,  v6,  6)  QK_OUT(u7,  v7,  7)
    QK_OUT(u8,  v8,  8)  QK_OUT(u9,  v9,  9)
    QK_OUT(u10, v10, 10) QK_OUT(u11, v11, 11)
    QK_OUT(u12, v12, 12) QK_OUT(u13, v13, 13)
    QK_OUT(u14, v14, 14) QK_OUT(u15, v15, 15)
}

// ---------------------------------------------------------------------------
// Kernel 2: energy + reversed-softmax -> attn (fp32)  (unchanged)
// ---------------------------------------------------------------------------
__global__ __launch_bounds__(256)
void attn_kernel(const float* __restrict__ Q_t, const float* __restrict__ K_t,
                 const float* __restrict__ Q_s, const float* __restrict__ K_s,
                 float* __restrict__ A_t, float* __restrict__ A_s) {
    const int zb = blockIdx.y, br = zb >> 5, b = zb & 31;
    const int M = br ? (HW_S / 8) : (HW_T / 8);
    const float* Qb = (br ? Q_s : Q_t) + (size_t)b * 32 * (br ? HW_S : HW_T);
    const float* Kb = (br ? K_s : K_t) + (size_t)b * 32 * (br ? HW_S : HW_T);
    float* attn = (br ? A_s : A_t) + (size_t)b * 65536;
    const int c0 = blockIdx.x * 32;

    __shared__ float sK[256][33];
    __shared__ float sQ[32][33];
    __shared__ float eT[32][260];

    const int tid = threadIdx.x;
    const int dx = tid & 31, cy = tid >> 5;
    float acc[4][8] = {};

    for (int m0 = 0; m0 < M; m0 += 32) {
        __syncthreads();
        {
            const int rr = tid >> 3;
            const int cc = (tid & 7) << 2;
#pragma unroll
            for (int p = 0; p < 8; p++) {
                const int row = (p << 5) + rr;
                const float4 v = *(const float4*)(Kb + (size_t)row * M + m0 + cc);
                sK[row][cc] = v.x; sK[row][cc + 1] = v.y;
                sK[row][cc + 2] = v.z; sK[row][cc + 3] = v.w;
            }
            const float4 qv = *(const float4*)(Qb + (size_t)(c0 + rr) * M + m0 + cc);
            sQ[rr][cc] = qv.x; sQ[rr][cc + 1] = qv.y;
            sQ[rr][cc + 2] = qv.z; sQ[rr][cc + 3] = qv.w;
        }
        __syncthreads();
#pragma unroll 2
        for (int m = 0; m < 32; m++) {
            float kv[8];
#pragma unroll
            for (int j = 0; j < 8; j++) kv[j] = sK[dx + (j << 5)][m];
#pragma unroll
            for (int i = 0; i < 4; i++) {
                const float qv = sQ[(cy << 2) + i][m];
#pragma unroll
                for (int j = 0; j < 8; j++) acc[i][j] = fmaf(qv, kv[j], acc[i][j]);
            }
        }
    }

#pragma unroll
    for (int i = 0; i < 4; i++)
#pragma unroll
        for (int j = 0; j < 8; j++)
            eT[(cy << 2) + i][dx + (j << 5)] = acc[i][j];
    __syncthreads();

    const int r = tid >> 3, s8 = tid & 7;
    float p[32];
    float mn = 3.0e38f;
#pragma unroll
    for (int m = 0; m < 32; m++) { p[m] = eT[r][s8 + (m << 3)]; mn = fminf(mn, p[m]); }
    mn = fminf(mn, __shfl_xor(mn, 1));
    mn = fminf(mn, __shfl_xor(mn, 2));
    mn = fminf(mn, __shfl_xor(mn, 4));
    float sum = 0.f;
#pragma unroll
    for (int m = 0; m < 32; m++) { p[m] = __expf(mn - p[m]); sum += p[m]; }
    sum += __shfl_xor(sum, 1);
    sum += __shfl_xor(sum, 2);
    sum += __shfl_xor(sum, 4);
    const float rinv = 1.0f / sum;
#pragma unroll
    for (int m = 0; m < 32; m++) eT[r][s8 + (m << 3)] = p[m] * rinv;
    __syncthreads();

    for (int idx = tid; idx < 2048; idx += 256) {
        const int row = idx >> 6, c4 = (idx & 63) << 2;
        const float4 v = *(const float4*)&eT[row][c4];
        *(float4*)(attn + (size_t)(c0 + row) * 256 + c4) = v;
    }
}

// ---------------------------------------------------------------------------
// Kernel 3: wgemm — W' = attn @ Vw (fp32), bf16 RTN epilogue (unchanged).
// ---------------------------------------------------------------------------
#define STA(P, OFF)                                           \
    sAf[(aslot * 4 + 0) * 260 + ar + (OFF)] = P.x;            \
    sAf[(aslot * 4 + 1) * 260 + ar + (OFF)] = P.y;            \
    sAf[(aslot * 4 + 2) * 260 + ar + (OFF)] = P.z;            \
    sAf[(aslot * 4 + 3) * 260 + ar + (OFF)] = P.w;

#define EPI_STO(AL, AR, CROW) {                               \
    const int c = (CROW);                                     \
    const size_t off0 = (size_t)c * 256 + n0 + (tx << 2);     \
    ushort4 h0, h1;                                           \
    h0.x = f2bf(AL.x); h0.y = f2bf(AL.y);                     \
    h0.z = f2bf(AL.z); h0.w = f2bf(AL.w);                     \
    h1.x = f2bf(AR.x); h1.y = f2bf(AR.y);                     \
    h1.z = f2bf(AR.z); h1.w = f2bf(AR.w);                     \
    *(ushort4*)(Co + off0) = h0;                              \
    *(ushort4*)(Co + off0 + 64) = h1; }

__global__ __launch_bounds__(256)
__attribute__((amdgpu_waves_per_eu(2, 2)))
void wgemm(const float* __restrict__ A_t, const float* __restrict__ A_s,
           const float* __restrict__ B_t, const float* __restrict__ B_s,
           ushort* __restrict__ W_t, ushort* __restrict__ W_s) {
    const int zb = blockIdx.z, br = zb >> 5, b = zb & 31;
    const int N = 256;
    const int n0 = blockIdx.x * 128;
    const float* A = (br ? A_s : A_t) + (size_t)b * 65536;
    const float* Bm = (br ? B_s : B_t);

    __shared__ float4 sA4[32][65];
    __shared__ float4 sB4[32][33];
    float* sAf = (float*)sA4;

    const int tid = threadIdx.x;
    const int tx = tid & 15, ty = tid >> 4;

    const int ar = tid >> 3, aslot = tid & 7;
    const int brow = tid >> 5, bcol = tid & 31;

    const float* Abase = A + (size_t)ar * 256 + aslot * 4;
    const float* Bbase = Bm + (size_t)brow * N + n0 + bcol * 4;

    float4 cL0{}, cL1{}, cL2{}, cL3{}, cL4{}, cL5{}, cL6{}, cL7{};
    float4 cL8{}, cL9{}, cL10{}, cL11{}, cL12{}, cL13{}, cL14{}, cL15{};
    float4 cR0{}, cR1{}, cR2{}, cR3{}, cR4{}, cR5{}, cR6{}, cR7{};
    float4 cR8{}, cR9{}, cR10{}, cR11{}, cR12{}, cR13{}, cR14{}, cR15{};
    float4 pa0, pa1, pa2, pa3, pa4, pa5, pa6, pa7, pb0, pb1, pb2, pb3;

    pa0 = *(const float4*)(Abase);
    pa1 = *(const float4*)(Abase + 8192);
    pa2 = *(const float4*)(Abase + 16384);
    pa3 = *(const float4*)(Abase + 24576);
    pa4 = *(const float4*)(Abase + 32768);
    pa5 = *(const float4*)(Abase + 40960);
    pa6 = *(const float4*)(Abase + 49152);
    pa7 = *(const float4*)(Abase + 57344);
    pb0 = *(const float4*)(Bbase);
    pb1 = *(const float4*)(Bbase + (size_t)8 * N);
    pb2 = *(const float4*)(Bbase + (size_t)16 * N);
    pb3 = *(const float4*)(Bbase + (size_t)24 * N);

    for (int k0 = 0; k0 < 256; k0 += 32) {
        __syncthreads();
        STA(pa0, 0)   STA(pa1, 32)  STA(pa2, 64)  STA(pa3, 96)
        STA(pa4, 128) STA(pa5, 160) STA(pa6, 192) STA(pa7, 224)
        sB4[brow][bcol]      = pb0;
        sB4[brow + 8][bcol]  = pb1;
        sB4[brow + 16][bcol] = pb2;
        sB4[brow + 24][bcol] = pb3;
        __syncthreads();

        if (k0 + 32 < 256) {
            const int kn = k0 + 32;
            pa0 = *(const float4*)(Abase + kn);
            pa1 = *(const float4*)(Abase + 8192 + kn);
            pa2 = *(const float4*)(Abase + 16384 + kn);
            pa3 = *(const float4*)(Abase + 24576 + kn);
            pa4 = *(const float4*)(Abase + 32768 + kn);
            pa5 = *(const float4*)(Abase + 40960 + kn);
            pa6 = *(const float4*)(Abase + 49152 + kn);
            pa7 = *(const float4*)(Abase + 57344 + kn);
            pb0 = *(const float4*)(Bbase + (size_t)kn * N);
            pb1 = *(const float4*)(Bbase + (size_t)(kn + 8) * N);
            pb2 = *(const float4*)(Bbase + (size_t)(kn + 16) * N);
            pb3 = *(const float4*)(Bbase + (size_t)(kn + 24) * N);
        }

#pragma unroll 4
        for (int k = 0; k < 32; k++) {
            const float4 a0 = sA4[k][ty];
            const float4 a1 = sA4[k][16 + ty];
            const float4 a2 = sA4[k][32 + ty];
            const float4 a3 = sA4[k][48 + ty];
            const float4 b0 = sB4[k][tx];
            const float4 b1 = sB4[k][16 + tx];
            FR8(cL0,  cR0,  a0.x) FR8(cL1,  cR1,  a0.y)
            FR8(cL2,  cR2,  a0.z) FR8(cL3,  cR3,  a0.w)
            FR8(cL4,  cR4,  a1.x) FR8(cL5,  cR5,  a1.y)
            FR8(cL6,  cR6,  a1.z) FR8(cL7,  cR7,  a1.w)
            FR8(cL8,  cR8,  a2.x) FR8(cL9,  cR9,  a2.y)
            FR8(cL10, cR10, a2.z) FR8(cL11, cR11, a2.w)
            FR8(cL12, cR12, a3.x) FR8(cL13, cR13, a3.y)
            FR8(cL14, cR14, a3.z) FR8(cL15, cR15, a3.w)
        }
    }

    ushort* Co = (br ? W_s : W_t) + (size_t)b * 65536;
    EPI_STO(cL0,  cR0,  (ty << 2) + 0)
    EPI_STO(cL1,  cR1,  (ty << 2) + 1)
    EPI_STO(cL2,  cR2,  (ty << 2) + 2)
    EPI_STO(cL3,  cR3,  (ty << 2) + 3)
    EPI_STO(cL4,  cR4,  64 + (ty << 2) + 0)
    EPI_STO(cL5,  cR5,  64 + (ty << 2) + 1)
    EPI_STO(cL6,  cR6,  64 + (ty << 2) + 2)
    EPI_STO(cL7,  cR7,  64 + (ty << 2) + 3)
    EPI_STO(cL8,  cR8,  128 + (ty << 2) + 0)
    EPI_STO(cL9,  cR9,  128 + (ty << 2) + 1)
    EPI_STO(cL10, cR10, 128 + (ty << 2) + 2)
    EPI_STO(cL11, cR11, 128 + (ty << 2) + 3)
    EPI_STO(cL12, cR12, 192 + (ty << 2) + 0)
    EPI_STO(cL13, cR13, 192 + (ty << 2) + 1)
    EPI_STO(cL14, cR14, 192 + (ty << 2) + 2)
    EPI_STO(cL15, cR15, 192 + (ty << 2) + 3)
}

// ---------------------------------------------------------------------------
// Kernel 4: b' GEMV (unchanged)
// ---------------------------------------------------------------------------
__global__ __launch_bounds__(256)
void bprime_kernel(const float* __restrict__ A_t, const float* __restrict__ A_s,
                   const float* __restrict__ vb_t, const float* __restrict__ vb_s,
                   float* __restrict__ bp_t, float* __restrict__ bp_s) {
    const int bx = blockIdx.x, br = bx >> 5, b = bx & 31;
    const float* A = (br ? A_s : A_t) + (size_t)b * 65536;
    const float* vb = br ? vb_s : vb_t;
    float* bp = (br ? bp_s : bp_t) + b * 256;
    __shared__ float svb[256];
    svb[threadIdx.x] = vb[threadIdx.x];
    __syncthreads();
    const int wave = threadIdx.x >> 6, lane = threadIdx.x & 63;
    for (int c = wave; c < 256; c += 4) {
        const float4 a = *(const float4*)(A + (size_t)c * 256 + (lane << 2));
        const int l4 = lane << 2;
        float s = a.x * svb[l4] + a.y * svb[l4 + 1] + a.z * svb[l4 + 2] + a.w * svb[l4 + 3];
#pragma unroll
        for (int off = 32; off > 0; off >>= 1) s += __shfl_down(s, off);
        if (lane == 0) bp[c] = s;
    }
}

// ---------------------------------------------------------------------------
// Kernel 5: vz_mfma — out = alpha*(W'@z + b') + z via bf16 MFMA 16x16x32.
//   r7 evidence: MfmaUtil 6%, VALUBusy 9%, occupancy 20% (waves cap + dead
//   blocks), traffic near-ideal -> latency-bound.  r8 restructure:
//   - NO sA: A-fragment == direct global b128 from W' (L2-resident, 128KB/b).
//     LDS 25.6KB -> 5KB (sB only) -> occupancy VGPR-bound ~4 blocks/CU.
//   - sB staged as ONE packed b128 write/thread (was 8 u16, 8-way conflict);
//     k-slot XOR-swizzled by (row>>3)&3 -> 2-way max, read applies same XOR.
//   - 1D grid of exactly 2560 live blocks (t: 16/batch, s: 64/batch).
//   - no waves_per_eu cap.
// ---------------------------------------------------------------------------
#define MF(CC, AF, BF) CC = __builtin_amdgcn_mfma_f32_16x16x32_bf16(AF, BF, CC, 0, 0, 0);

#define EPO(CC, R, C) {                                                     \
    const int cg = (w << 6) + ((R) << 4) + (lk << 2);                       \
    const size_t nn = (size_t)(n0 + ((C) << 4) + lr);                       \
    const size_t o0 = (size_t)(cg + 0) * N + nn;                            \
    const size_t o1 = (size_t)(cg + 1) * N + nn;                            \
    const size_t o2 = (size_t)(cg + 2) * N + nn;                            \
    const size_t o3 = (size_t)(cg + 3) * N + nn;                            \
    O[o0] = fmaf(alpha, CC.x + bp[cg + 0], Z[o0]);                          \
    O[o1] = fmaf(alpha, CC.y + bp[cg + 1], Z[o1]);                          \
    O[o2] = fmaf(alpha, CC.z + bp[cg + 2], Z[o2]);                          \
    O[o3] = fmaf(alpha, CC.w + bp[cg + 3], Z[o3]); }

__global__ __launch_bounds__(256)
void vz_mfma(const ushort* __restrict__ W_t, const ushort* __restrict__ W_s,
             const float* __restrict__ z_t, const float* __restrict__ z_s,
             float* __restrict__ O_t, float* __restrict__ O_s,
             const float* __restrict__ bp_t, const float* __restrict__ bp_s,
             const float* __restrict__ alpha_p, const float* __restrict__ beta_p,
             int N_t, int N_s) {
    // 1D compact grid: first 512 blocks -> t (16 n-blocks x 32 b),
    // next 2048 -> s (64 n-blocks x 32 b).
    const int bid = blockIdx.x;
    int br, b, nb;
    if (bid < 512) { br = 0; b = bid >> 4; nb = bid & 15; }
    else { const int r = bid - 512; br = 1; b = r >> 6; nb = r & 63; }
    const int N = br ? N_s : N_t;
    const int n0 = nb * 64;
    const ushort* Wb = (br ? W_s : W_t) + (size_t)b * 65536;
    const float* Z = (br ? z_s : z_t) + (size_t)b * 256 * (size_t)N;

    __shared__ ushort sB[64 * 40];              // 5 KiB: [n][40] rows, swizzled k-slots

    const int tid = threadIdx.x;
    const int w = tid >> 6, l = tid & 63;
    const int lr = l & 15, lk = l >> 4;

    // z staging: thread (zn, zw) loads z[k = zw*8+p][n0+zn], p=0..7 (coalesced
    // 256B per wave per p), packs to 8 bf16, ONE b128 write (swizzled slot).
    const int zn = tid & 63, zw = tid >> 6;
    const float* Bbase = Z + (size_t)(zw * 8) * N + n0 + zn;
    const int sbw = zn * 40 + ((zw << 3) ^ (((zn >> 3) & 3) << 3));

    // A fragments: direct global.  wave w rows w*64 + r*16 + lr, slot lk*8.
    const ushort* Arow = Wb + (size_t)(w * 64 + lr) * 256 + lk * 8;

    // B-frag read offsets (swizzle matches write)
    const int rb0 = (0 * 16 + lr) * 40 + ((lk << 3) ^ ((((0 * 16 + lr) >> 3) & 3) << 3));
    const int rb1 = (1 * 16 + lr) * 40 + ((lk << 3) ^ ((((1 * 16 + lr) >> 3) & 3) << 3));
    const int rb2 = (2 * 16 + lr) * 40 + ((lk << 3) ^ ((((2 * 16 + lr) >> 3) & 3) << 3));
    const int rb3 = (3 * 16 + lr) * 40 + ((lk << 3) ^ ((((3 * 16 + lr) >> 3) & 3) << 3));

    f32x4 c00{}, c01{}, c02{}, c03{};
    f32x4 c10{}, c11{}, c12{}, c13{};
    f32x4 c20{}, c21{}, c22{}, c23{};
    f32x4 c30{}, c31{}, c32{}, c33{};

    float qz0, qz1, qz2, qz3, qz4, qz5, qz6, qz7;
    short8v pa0, pa1, pa2, pa3;

    // prologue prefetch (k0 = 0)
    qz0 = Bbase[0];
    qz1 = Bbase[(size_t)1 * N];
    qz2 = Bbase[(size_t)2 * N];
    qz3 = Bbase[(size_t)3 * N];
    qz4 = Bbase[(size_t)4 * N];
    qz5 = Bbase[(size_t)5 * N];
    qz6 = Bbase[(size_t)6 * N];
    qz7 = Bbase[(size_t)7 * N];
    pa0 = *(const short8v*)(Arow);
    pa1 = *(const short8v*)(Arow + 16 * 256);
    pa2 = *(const short8v*)(Arow + 32 * 256);
    pa3 = *(const short8v*)(Arow + 48 * 256);

    for (int k0 = 0; k0 < 256; k0 += 32) {
        __syncthreads();                        // sB free to overwrite
        uint4 pk;
        pk.x = pk2(qz0, qz1); pk.y = pk2(qz2, qz3);
        pk.z = pk2(qz4, qz5); pk.w = pk2(qz6, qz7);
        *(uint4*)&sB[sbw] = pk;
        __syncthreads();

        const short8v a0 = pa0, a1 = pa1, a2 = pa2, a3 = pa3;
        if (k0 + 32 < 256) {                    // prefetch under MFMA
            const int kn = k0 + 32;
            const float* Bn = Bbase + (size_t)kn * N;
            qz0 = Bn[0];
            qz1 = Bn[(size_t)1 * N];
            qz2 = Bn[(size_t)2 * N];
            qz3 = Bn[(size_t)3 * N];
            qz4 = Bn[(size_t)4 * N];
            qz5 = Bn[(size_t)5 * N];
            qz6 = Bn[(size_t)6 * N];
            qz7 = Bn[(size_t)7 * N];
            pa0 = *(const short8v*)(Arow + kn);
            pa1 = *(const short8v*)(Arow + 16 * 256 + kn);
            pa2 = *(const short8v*)(Arow + 32 * 256 + kn);
            pa3 = *(const short8v*)(Arow + 48 * 256 + kn);
        }

        const short8v b0 = *(const short8v*)&sB[rb0];
        const short8v b1 = *(const short8v*)&sB[rb1];
        const short8v b2 = *(const short8v*)&sB[rb2];
        const short8v b3 = *(const short8v*)&sB[rb3];

        MF(c00, a0, b0) MF(c01, a0, b1) MF(c02, a0, b2) MF(c03, a0, b3)
        MF(c10, a1, b0) MF(c11, a1, b1) MF(c12, a1, b2) MF(c13, a1, b3)
        MF(c20, a2, b0) MF(c21, a2, b1) MF(c22, a2, b2) MF(c23, a2, b3)
        MF(c30, a3, b0) MF(c31, a3, b1) MF(c32, a3, b2) MF(c33, a3, b3)
    }

    const float alpha = br ? beta_p[0] : alpha_p[0];
    const float* bp = (br ? bp_s : bp_t) + b * 256;
    float* O = (br ? O_s : O_t) + (size_t)b * 256 * (size_t)N;

    EPO(c00, 0, 0) EPO(c01, 0, 1) EPO(c02, 0, 2) EPO(c03, 0, 3)
    EPO(c10, 1, 0) EPO(c11, 1, 1) EPO(c12, 1, 2) EPO(c13, 1, 3)
    EPO(c20, 2, 0) EPO(c21, 2, 1) EPO(c22, 2, 2) EPO(c23, 2, 3)
    EPO(c30, 3, 0) EPO(c31, 3, 1) EPO(c32, 3, 2) EPO(c33, 3, 3)
}

// ---------------------------------------------------------------------------
extern "C" void kernel_launch(void* const* d_in, const int* in_sizes, int n_in,
                              void* d_out, int out_size, void* d_ws, size_t ws_size,
                              hipStream_t stream) {
    const float* rgb_t = (const float*)d_in[0];
    const float* rgb_s = (const float*)d_in[1];
    const float* z_t   = (const float*)d_in[2];
    const float* z_s   = (const float*)d_in[3];
    const float* tq_w  = (const float*)d_in[4];
    const float* tq_b  = (const float*)d_in[5];
    const float* tk_w  = (const float*)d_in[6];
    const float* tk_b  = (const float*)d_in[7];
    const float* tv_w  = (const float*)d_in[8];
    const float* tv_b  = (const float*)d_in[9];
    const float* sq_w  = (const float*)d_in[10];
    const float* sq_b  = (const float*)d_in[11];
    const float* sk_w  = (const float*)d_in[12];
    const float* sk_b  = (const float*)d_in[13];
    const float* sv_w  = (const float*)d_in[14];
    const float* sv_b  = (const float*)d_in[15];
    const float* alpha = (const float*)d_in[16];
    const float* beta  = (const float*)d_in[17];

    // workspace layout (fp32).  W'(bf16) aliases the Q/K region (attn is the
    // last reader of Q/K; wgemm runs after attn_kernel).
    float* ws  = (float*)d_ws;
    float* At  = ws;                       // 32*256*256   attn (t)
    float* As_ = At + 2097152;             // attn (s)
    float* bt  = As_ + 2097152;            // 32*256 b' (t)
    float* bs  = bt + 8192;                // b' (s)
    float* Qt  = bs + 8192;                // 32*32*1024
    float* Kt  = Qt + 1048576;
    float* Qs  = Kt + 1048576;             // 32*32*4096
    float* Ks  = Qs + 4194304;
    float* Wct = Ks + 4194304;             // 256*64 k-major weights (t)
    float* Wcs = Wct + 16384;              // 256*64 (s)
    ushort* Wbt = (ushort*)Qt;             // alias: W' bf16 (t), 4 MB over Qt
    ushort* Wbs = (ushort*)Qs;             // alias: W' bf16 (s), 4 MB over Qs

    float* out_t = (float*)d_out;
    float* out_s = out_t + (size_t)32 * 256 * HW_T;

    wprep_kernel<<<dim3(2), 256, 0, stream>>>(tq_w, tk_w, sq_w, sk_w, Wct, Wcs);

    qk_gemm<<<dim3(8, 64), 256, 0, stream>>>(
        rgb_t, rgb_s, Wct, Wcs, tq_b, tk_b, sq_b, sk_b, Qt, Kt, Qs, Ks);

    attn_kernel<<<dim3(8, 64), 256, 0, stream>>>(Qt, Kt, Qs, Ks, At, As_);

    bprime_kernel<<<dim3(64), 256, 0, stream>>>(At, As_, tv_b, sv_b, bt, bs);

    wgemm<<<dim3(2, 1, 64), 256, 0, stream>>>(At, As_, tv_w, sv_w, Wbt, Wbs);

    vz_mfma<<<dim3(2560), 256, 0, stream>>>(
        Wbt, Wbs, z_t, z_s, out_t, out_s, bt, bs, alpha, beta, HW_T, HW_S);
}